// Round 2
// baseline (473.283 us; speedup 1.0000x reference)
//
#include <hip/hip_runtime.h>

#define D 128
#define PCHUNK 4096
#define SCAP 8192

typedef short bf16x8 __attribute__((ext_vector_type(8)));
typedef float f32x4 __attribute__((ext_vector_type(4)));

__device__ __forceinline__ ushort f2b(float f){
  unsigned u = __builtin_bit_cast(unsigned, f);
  u += 0x7fffu + ((u >> 16) & 1u);          // round-to-nearest-even
  return (ushort)(u >> 16);
}
__device__ __forceinline__ float b2f(ushort h){
  unsigned u = ((unsigned)h) << 16;
  return __builtin_bit_cast(float, u);
}

// ---------------- P0: coarse bucket histogram (bucket = dst>>8) ----------------
__global__ __launch_bounds__(256) void k_p0(const int* __restrict__ dst,
                                            int* __restrict__ bcnt, int E){
  __shared__ int h[512];
  for (int u=threadIdx.x; u<512; u+=256) h[u]=0;
  __syncthreads();
  for (long long i=(long long)blockIdx.x*256+threadIdx.x; i<E; i+=(long long)gridDim.x*256)
    atomicAdd(&h[dst[i]>>8], 1);
  __syncthreads();
  for (int u=threadIdx.x; u<512; u+=256) if (h[u]) atomicAdd(&bcnt[u], h[u]);
}

// ---------------- P1: scan buckets -> base & cursor ----------------
__global__ void k_bscan(const int* __restrict__ bcnt, int* __restrict__ bbase,
                        int* __restrict__ bcur, int nb, int E){
  __shared__ int sh[1024];
  int t = threadIdx.x;
  int v = (t<nb) ? bcnt[t] : 0;
  sh[t]=v; __syncthreads();
  for (int off=1; off<1024; off<<=1){
    int add = (t>=off)?sh[t-off]:0;
    __syncthreads();
    sh[t]+=add;
    __syncthreads();
  }
  if (t<nb){ int e=sh[t]-v; bbase[t]=e; bcur[t]=e; }
  if (t==nb) bbase[t]=E;
}

// ---------------- P2: LDS-binned partition of (src,dst) into buckets ----------------
__global__ __launch_bounds__(256) void k_part(const int* __restrict__ src,
        const int* __restrict__ dst, int* __restrict__ bcur,
        int2* __restrict__ pairs, int E){
  __shared__ int hist[512], offA[512], offB[512], gbase[512];
  __shared__ int sS[PCHUNK], sD[PCHUNK];
  const int t = threadIdx.x;
  const int base = blockIdx.x * PCHUNK;
  const int cnt = min(PCHUNK, E - base);
  for (int u=t; u<512; u+=256) hist[u]=0;
  __syncthreads();
  int rs[16], rd[16];
  #pragma unroll
  for (int j=0;j<16;j++){
    int li = j*256 + t;
    if (li < cnt){
      rs[j]=src[base+li]; rd[j]=dst[base+li];
      atomicAdd(&hist[rd[j]>>8],1);
    } else { rs[j]=0; rd[j]=-1; }
  }
  __syncthreads();
  int *cur=offA, *nxt=offB;
  for (int u=t; u<512; u+=256) cur[u]=hist[u];
  __syncthreads();
  for (int off=1; off<512; off<<=1){
    for (int u=t; u<512; u+=256) nxt[u] = cur[u] + ((u>=off)?cur[u-off]:0);
    __syncthreads();
    int* tmp=cur; cur=nxt; nxt=tmp;
  }
  for (int u=t; u<512; u+=256) nxt[u] = cur[u]-hist[u];
  __syncthreads();
  #pragma unroll
  for (int j=0;j<16;j++){
    if (j*256+t < cnt){
      int b = rd[j]>>8;
      int p = atomicAdd(&nxt[b],1);
      sS[p]=rs[j]; sD[p]=rd[j];
    }
  }
  __syncthreads();
  for (int u=t; u<512; u+=256){
    int c = hist[u];
    if (c>0) gbase[u] = atomicAdd(&bcur[u], c);
  }
  __syncthreads();
  #pragma unroll
  for (int j=0;j<16;j++){
    int idx = j*256+t;
    if (idx<cnt){
      int d = sD[idx]; int b = d>>8;
      int gpos = gbase[b] + (idx - (cur[b]-hist[b]));
      pairs[gpos] = make_int2(sS[idx], d);
    }
  }
}

// ---------------- P3: per-bucket exact counting sort -> slots + offs ----------------
__global__ __launch_bounds__(256) void k_sortb(const int2* __restrict__ pairs,
        const int* __restrict__ bbase, int* __restrict__ offs,
        int* __restrict__ slots, int N, int NB){
  __shared__ int nh[256], nc[256], sc[256];
  __shared__ int stage[SCAP];
  const int b = blockIdx.x, t = threadIdx.x;
  const int base = bbase[b];
  const int cnt  = bbase[b+1] - base;
  nh[t]=0; __syncthreads();
  for (int i=t;i<cnt;i+=256) atomicAdd(&nh[pairs[base+i].y & 255],1);
  __syncthreads();
  int v = nh[t];
  sc[t]=v; __syncthreads();
  for (int off=1; off<256; off<<=1){
    int add = (t>=off)?sc[t-off]:0;
    __syncthreads();
    sc[t]+=add;
    __syncthreads();
  }
  int excl = sc[t]-v;
  nc[t]=excl;
  int node = (b<<8)+t;
  if (node<N) offs[node]=base+excl;
  if (b==NB-1 && t==0) offs[N]=bbase[NB];
  __syncthreads();
  if (cnt<=SCAP){
    for (int i=t;i<cnt;i+=256){
      int2 p = pairs[base+i];
      int pos = atomicAdd(&nc[p.y & 255],1);
      stage[pos]=p.x;
    }
    __syncthreads();
    for (int i=t;i<cnt;i+=256) slots[base+i]=stage[i];
  } else {
    for (int i=t;i<cnt;i+=256){
      int2 p = pairs[base+i];
      int pos = atomicAdd(&nc[p.y & 255],1);
      slots[base+pos]=p.x;
    }
  }
}

// ---------------- f32 -> bf16 cast ----------------
__global__ __launch_bounds__(256) void k_xcast(const float* __restrict__ x,
                                               ushort* __restrict__ xb, long long n4){
  long long i = (long long)blockIdx.x*256 + threadIdx.x;
  const long long stride = (long long)gridDim.x*256;
  for (; i < n4; i += stride){
    float4 v = reinterpret_cast<const float4*>(x)[i];
    ushort4 o;
    o.x = f2b(v.x); o.y = f2b(v.y); o.z = f2b(v.z); o.w = f2b(v.w);
    reinterpret_cast<ushort4*>(xb)[i] = o;
  }
}

// ---------------- weight transpose+cast: Wb[c*K + k0 + k] = bf16(W[k][c]) ----------------
__global__ void k_wt(const float* __restrict__ W, ushort* __restrict__ Wb, int K, int k0){
  int idx = blockIdx.x*256 + threadIdx.x;   // 0..16383
  int k = idx >> 7, c = idx & 127;
  Wb[(size_t)c*K + k0 + k] = f2b(W[idx]);
}

// ---------------- gather-mean (bf16 in/out): 64 threads/node, pipelined 8-edge groups ----
__global__ __launch_bounds__(256) void k_gatherb(const ushort* __restrict__ Xb,
        const int* __restrict__ slots, const int* __restrict__ offs,
        ushort* __restrict__ meanb, int N){
  int node = blockIdx.x*4 + (threadIdx.x >> 6);
  int c2 = (threadIdx.x & 63) * 2;            // this lane's channel pair
  if (node >= N) return;
  const int beg = offs[node], end = offs[node+1];
  float sx0=0,sy0=0,sx1=0,sy1=0,sx2=0,sy2=0,sx3=0,sy3=0;
  int j = beg;
  // align to int4 boundary
  while (j < end && (j & 3)){
    unsigned u = *reinterpret_cast<const unsigned*>(&Xb[(size_t)slots[j]*D + c2]);
    sx0 += b2f((ushort)u); sy0 += b2f((ushort)(u>>16));
    ++j;
  }
  const int nfull = (end - j) >> 2;           // # of aligned 4-edge groups
  const int4* sp = reinterpret_cast<const int4*>(slots + j);

#define G8(ia, ib) { \
    unsigned u0 = *reinterpret_cast<const unsigned*>(&Xb[(size_t)(ia).x*D + c2]); \
    unsigned u1 = *reinterpret_cast<const unsigned*>(&Xb[(size_t)(ia).y*D + c2]); \
    unsigned u2 = *reinterpret_cast<const unsigned*>(&Xb[(size_t)(ia).z*D + c2]); \
    unsigned u3 = *reinterpret_cast<const unsigned*>(&Xb[(size_t)(ia).w*D + c2]); \
    unsigned u4 = *reinterpret_cast<const unsigned*>(&Xb[(size_t)(ib).x*D + c2]); \
    unsigned u5 = *reinterpret_cast<const unsigned*>(&Xb[(size_t)(ib).y*D + c2]); \
    unsigned u6 = *reinterpret_cast<const unsigned*>(&Xb[(size_t)(ib).z*D + c2]); \
    unsigned u7 = *reinterpret_cast<const unsigned*>(&Xb[(size_t)(ib).w*D + c2]); \
    sx0 += b2f((ushort)u0); sy0 += b2f((ushort)(u0>>16)); \
    sx1 += b2f((ushort)u1); sy1 += b2f((ushort)(u1>>16)); \
    sx2 += b2f((ushort)u2); sy2 += b2f((ushort)(u2>>16)); \
    sx3 += b2f((ushort)u3); sy3 += b2f((ushort)(u3>>16)); \
    sx0 += b2f((ushort)u4); sy0 += b2f((ushort)(u4>>16)); \
    sx1 += b2f((ushort)u5); sy1 += b2f((ushort)(u5>>16)); \
    sx2 += b2f((ushort)u6); sy2 += b2f((ushort)(u6>>16)); \
    sx3 += b2f((ushort)u7); sy3 += b2f((ushort)(u7>>16)); }

  int g = 0;
  if (nfull >= 2){
    int4 ia = sp[0], ib = sp[1];
    for (g = 2; g + 2 <= nfull; g += 2){
      int4 na = sp[g], nb = sp[g+1];     // next-group indices in flight during gathers
      G8(ia, ib);
      ia = na; ib = nb;
    }
    G8(ia, ib);
  }
  if (g < nfull){                        // one leftover 4-edge group
    int4 ia = sp[g];
    unsigned u0 = *reinterpret_cast<const unsigned*>(&Xb[(size_t)ia.x*D + c2]);
    unsigned u1 = *reinterpret_cast<const unsigned*>(&Xb[(size_t)ia.y*D + c2]);
    unsigned u2 = *reinterpret_cast<const unsigned*>(&Xb[(size_t)ia.z*D + c2]);
    unsigned u3 = *reinterpret_cast<const unsigned*>(&Xb[(size_t)ia.w*D + c2]);
    sx0 += b2f((ushort)u0); sy0 += b2f((ushort)(u0>>16));
    sx1 += b2f((ushort)u1); sy1 += b2f((ushort)(u1>>16));
    sx2 += b2f((ushort)u2); sy2 += b2f((ushort)(u2>>16));
    sx3 += b2f((ushort)u3); sy3 += b2f((ushort)(u3>>16));
  }
  j += 4*nfull;
  for (; j < end; ++j){
    unsigned u = *reinterpret_cast<const unsigned*>(&Xb[(size_t)slots[j]*D + c2]);
    sx0 += b2f((ushort)u); sy0 += b2f((ushort)(u>>16));
  }
#undef G8
  float deg = (float)(end - beg);
  float rc = deg > 0.f ? 1.0f/deg : 0.f;
  unsigned o = (unsigned)f2b((sx0+sx1+sx2+sx3)*rc)
             | ((unsigned)f2b((sy0+sy1+sy2+sy3)*rc) << 16);
  *reinterpret_cast<unsigned*>(&meanb[(size_t)node*D + c2]) = o;
}

// ---------------- barrier-free MFMA GEMM: wave = 16 rows x 128 cols ----------------
// C = [A0 | A1] @ Wb^T + bias (K=256), optional fused skip Ck = A0 @ Wk^T + biasK (K=128).
// Block = 64 rows (4 waves), no LDS staging, W served from L2 (shared by all waves),
// A prefetched 2 k-steps ahead; W loads issued before the A-prefetch so the MFMA
// vmcnt-wait leaves the prefetch in flight.
template<bool SKIP>
__global__ __launch_bounds__(256) void k_gemm(
    const ushort* __restrict__ A0, const ushort* __restrict__ A1,
    const ushort* __restrict__ Wb, const ushort* __restrict__ Wk,
    const float* __restrict__ bias, const float* __restrict__ biasK,
    ushort* __restrict__ C, ushort* __restrict__ Ck,
    float* __restrict__ gS, float* __restrict__ gQ,
    float* __restrict__ gSK, float* __restrict__ gQK, int N)
{
  __shared__ float shS[128], shQ[128], shSK[SKIP?128:1], shQK[SKIP?128:1];
  const int tid = threadIdx.x;
  if (tid < 128){ shS[tid]=0.f; shQ[tid]=0.f; if (SKIP){ shSK[tid]=0.f; shQK[tid]=0.f; } }
  __syncthreads();

  const int lane = tid & 63, wid = tid >> 6;
  const int lr = lane & 15, kq = lane >> 4;
  const int row16 = blockIdx.x*64 + wid*16;       // wave's 16-row base

  int arow = row16 + lr; if (arow >= N) arow = N-1;
  const size_t aoff = (size_t)arow * D + kq*8;    // element offset of this lane's A frag

  f32x4 acc[8], accK[SKIP?8:1];
  #pragma unroll
  for (int n=0;n<8;n++) acc[n] = (f32x4){0.f,0.f,0.f,0.f};
  if (SKIP){
    #pragma unroll
    for (int n=0;n<8;n++) accK[n] = (f32x4){0.f,0.f,0.f,0.f};
  }

  // A prefetch depth 2
  int4 a0 = *reinterpret_cast<const int4*>(A0 + aoff);
  int4 a1 = *reinterpret_cast<const int4*>(A0 + aoff + 32);

  #pragma unroll
  for (int t=0; t<8; ++t){
    // W loads for this k-step (L2-resident; same addrs for every wave)
    int4 wv[8];
    #pragma unroll
    for (int n=0;n<8;n++)
      wv[n] = *reinterpret_cast<const int4*>(Wb + (size_t)(16*n+lr)*256 + t*32 + kq*8);
    int4 wk[SKIP?8:1];
    if (SKIP && t < 4){
      #pragma unroll
      for (int n=0;n<8;n++)
        wk[n] = *reinterpret_cast<const int4*>(Wk + (size_t)(16*n+lr)*128 + t*32 + kq*8);
    }
    // A prefetch for t+2, issued last so MFMA waits keep it outstanding
    int4 an = make_int4(0,0,0,0);
    if (t+2 < 8){
      const ushort* ab = (t+2 >= 4) ? A1 : A0;
      an = *reinterpret_cast<const int4*>(ab + aoff + ((t+2)&3)*32);
    }
    bf16x8 af = __builtin_bit_cast(bf16x8, a0);
    #pragma unroll
    for (int n=0;n<8;n++)
      acc[n] = __builtin_amdgcn_mfma_f32_16x16x32_bf16(
          af, __builtin_bit_cast(bf16x8, wv[n]), acc[n], 0, 0, 0);
    if (SKIP && t < 4){
      #pragma unroll
      for (int n=0;n<8;n++)
        accK[n] = __builtin_amdgcn_mfma_f32_16x16x32_bf16(
            af, __builtin_bit_cast(bf16x8, wk[n]), accK[n], 0, 0, 0);
    }
    a0 = a1; a1 = an;
  }

  // epilogue: bias + bf16 store + BN partial stats
  #pragma unroll
  for (int n=0;n<8;n++){
    const int col = 16*n + lr;
    const float bv = bias[col];
    const float bkv = SKIP ? biasK[col] : 0.f;
    float s=0.f, q=0.f, sk=0.f, qk=0.f;
    #pragma unroll
    for (int r=0;r<4;r++){
      int row = row16 + kq*4 + r;
      if (row < N){
        float v = acc[n][r] + bv;
        C[(size_t)row*D + col] = f2b(v);
        s += v; q += v*v;
        if (SKIP){
          float u = accK[n][r] + bkv;
          Ck[(size_t)row*D + col] = f2b(u);
          sk += u; qk += u*u;
        }
      }
    }
    s += __shfl_xor(s,16); s += __shfl_xor(s,32);
    q += __shfl_xor(q,16); q += __shfl_xor(q,32);
    if (SKIP){
      sk += __shfl_xor(sk,16); sk += __shfl_xor(sk,32);
      qk += __shfl_xor(qk,16); qk += __shfl_xor(qk,32);
    }
    if (kq == 0){
      atomicAdd(&shS[col], s);
      atomicAdd(&shQ[col], q);
      if (SKIP){
        atomicAdd(&shSK[col], sk);
        atomicAdd(&shQK[col], qk);
      }
    }
  }
  __syncthreads();
  if (tid < 128){
    unsafeAtomicAdd(&gS[tid], shS[tid]);
    unsafeAtomicAdd(&gQ[tid], shQ[tid]);
    if (SKIP){
      unsafeAtomicAdd(&gSK[tid], shSK[tid]);
      unsafeAtomicAdd(&gQK[tid], shQK[tid]);
    }
  }
}

// ---------------- BN finalize ----------------
__global__ void k_bnfin(const float* __restrict__ sum, const float* __restrict__ sq,
                        const float* __restrict__ g, const float* __restrict__ be,
                        float* __restrict__ bnA, float* __restrict__ bnB, float invN){
  int c = threadIdx.x;
  float m = sum[c]*invN;
  float v = sq[c]*invN - m*m;
  float a = g[c]*rsqrtf(fmaxf(v, 0.f) + 1e-5f);
  bnA[c] = a;
  bnB[c] = be[c] - m*a;
}

// ---------------- BN + ReLU, bf16 in -> bf16 out ----------------
__global__ __launch_bounds__(256) void k_bnrelub(const ushort* __restrict__ hpre,
      ushort* __restrict__ hb,
      const float* __restrict__ A, const float* __restrict__ Bp, long long n4){
  long long i = (long long)blockIdx.x*256 + threadIdx.x;
  const long long stride = (long long)gridDim.x*256;
  for (; i < n4; i += stride){
    int c = ((int)(i & 31)) << 2;
    float4 a = *reinterpret_cast<const float4*>(A + c);
    float4 b = *reinterpret_cast<const float4*>(Bp + c);
    ushort4 hv = reinterpret_cast<const ushort4*>(hpre)[i];
    ushort4 o;
    o.x = f2b(fmaxf(a.x*b2f(hv.x) + b.x, 0.f));
    o.y = f2b(fmaxf(a.y*b2f(hv.y) + b.y, 0.f));
    o.z = f2b(fmaxf(a.z*b2f(hv.z) + b.z, 0.f));
    o.w = f2b(fmaxf(a.w*b2f(hv.w) + b.w, 0.f));
    reinterpret_cast<ushort4*>(hb)[i] = o;
  }
}

// ---------------- final: out = relu(bn2(h2) + bn3(skip)), f32 out ----------------
__global__ __launch_bounds__(256) void k_final(const ushort* __restrict__ h2,
      const ushort* __restrict__ sk, float* __restrict__ out,
      const float* __restrict__ A2, const float* __restrict__ B2,
      const float* __restrict__ A3, const float* __restrict__ B3, long long n4){
  long long i = (long long)blockIdx.x*256 + threadIdx.x;
  const long long stride = (long long)gridDim.x*256;
  for (; i < n4; i += stride){
    int c = ((int)(i & 31)) << 2;
    float4 a2 = *reinterpret_cast<const float4*>(A2 + c);
    float4 b2 = *reinterpret_cast<const float4*>(B2 + c);
    float4 a3 = *reinterpret_cast<const float4*>(A3 + c);
    float4 b3 = *reinterpret_cast<const float4*>(B3 + c);
    ushort4 h = reinterpret_cast<const ushort4*>(h2)[i];
    ushort4 s = reinterpret_cast<const ushort4*>(sk)[i];
    float4 v;
    v.x = fmaxf(a2.x*b2f(h.x) + b2.x + a3.x*b2f(s.x) + b3.x, 0.f);
    v.y = fmaxf(a2.y*b2f(h.y) + b2.y + a3.y*b2f(s.y) + b3.y, 0.f);
    v.z = fmaxf(a2.z*b2f(h.z) + b2.z + a3.z*b2f(s.z) + b3.z, 0.f);
    v.w = fmaxf(a2.w*b2f(h.w) + b2.w + a3.w*b2f(s.w) + b3.w, 0.f);
    reinterpret_cast<float4*>(out)[i] = v;
  }
}

extern "C" void kernel_launch(void* const* d_in, const int* in_sizes, int n_in,
                              void* d_out, int out_size, void* d_ws, size_t ws_size,
                              hipStream_t stream) {
  const float* x        = (const float*)d_in[0];
  const int*   src      = (const int*)  d_in[1];
  const int*   dst      = (const int*)  d_in[2];
  const float* w_self1  = (const float*)d_in[3];
  const float* w_neigh1 = (const float*)d_in[4];
  const float* b1       = (const float*)d_in[5];
  const float* w_self2  = (const float*)d_in[6];
  const float* w_neigh2 = (const float*)d_in[7];
  const float* b2       = (const float*)d_in[8];
  const float* w_skip   = (const float*)d_in[9];
  const float* b_skip   = (const float*)d_in[10];
  const float* g1       = (const float*)d_in[11];
  const float* be1      = (const float*)d_in[12];
  const float* g2       = (const float*)d_in[13];
  const float* be2      = (const float*)d_in[14];
  const float* g3       = (const float*)d_in[15];
  const float* be3      = (const float*)d_in[16];
  (void)n_in; (void)ws_size;

  const int N = in_sizes[0] / D;
  const int E = in_sizes[1];
  const int NB = (N + 255) >> 8;
  float* out = (float*)d_out;

  // ---- workspace layout ----
  char* p = (char*)d_ws;
  const size_t nd2 = (((size_t)N * D * 2) + 255) / 256 * 256;   // bf16 [N][D]
  ushort* meanb  = (ushort*)p; p += nd2;
  ushort* h1b    = (ushort*)p; p += nd2;
  ushort* hpre_b = (ushort*)p; p += nd2;     // h1pre, then h2pre (aliased)
  ushort* skip_b = (ushort*)p; p += nd2;
  ushort* Wb1    = (ushort*)p; p += 256*128*2;
  ushort* Wb2    = (ushort*)p; p += 256*128*2;
  ushort* Wb3    = (ushort*)p; p += 128*128*2;
  int*    offs   = (int*)p;   p += (((size_t)(N+1)*4) + 255) / 256 * 256;
  int*    bcnt   = (int*)p;   p += 2304;
  float*  st     = (float*)p; p += 1536*sizeof(float);
  int*    bbase  = (int*)p;   p += 2304;
  int*    bcur   = (int*)p;   p += 2048;
  float *sum1=st,      *sq1=st+128,  *sum2=st+256, *sq2=st+384, *sum3=st+512, *sq3=st+640;
  float *bnA1=st+768,  *bnB1=st+896, *bnA2=st+1024,*bnB2=st+1152,*bnA3=st+1280,*bnB3=st+1408;

  // scratch in d_out (dead before k_final rewrites all of d_out)
  const size_t slpad = (((size_t)E*4) + 255) / 256 * 256;
  const size_t xbpad = (((size_t)N*D*2) + 255) / 256 * 256;
  int*    slots = (int*)d_out;
  ushort* xb    = (ushort*)((char*)d_out + slpad);
  int2*   pairs = (int2*)((char*)d_out + slpad + xbpad);

  hipMemsetAsync(bcnt, 0, 2304 + 1536*sizeof(float), stream);

  const long long n4 = (long long)N * D / 4;

  // --- casts / weight prep ---
  k_xcast<<<2048, 256, 0, stream>>>(x, xb, n4);
  k_wt<<<64, 256, 0, stream>>>(w_self1,  Wb1, 256, 0);
  k_wt<<<64, 256, 0, stream>>>(w_neigh1, Wb1, 256, 128);
  k_wt<<<64, 256, 0, stream>>>(w_self2,  Wb2, 256, 0);
  k_wt<<<64, 256, 0, stream>>>(w_neigh2, Wb2, 256, 128);
  k_wt<<<64, 256, 0, stream>>>(w_skip,   Wb3, 128, 0);

  // --- CSR build via 2-level counting sort ---
  k_p0<<<1024, 256, 0, stream>>>(dst, bcnt, E);
  k_bscan<<<1, 1024, 0, stream>>>(bcnt, bbase, bcur, NB, E);
  k_part<<<(E + PCHUNK - 1)/PCHUNK, 256, 0, stream>>>(src, dst, bcur, pairs, E);
  k_sortb<<<NB, 256, 0, stream>>>(pairs, bbase, offs, slots, N, NB);

  const int gablocks = (N + 3) / 4;
  const int gmblocks = (N + 63) / 64;
  const float invN = 1.0f / (float)N;

  // --- layer 1 ---
  k_gatherb<<<gablocks, 256, 0, stream>>>(xb, slots, offs, meanb, N);
  k_gemm<false><<<gmblocks, 256, 0, stream>>>(xb, meanb, Wb1, nullptr, b1, nullptr,
                                              hpre_b, nullptr, sum1, sq1, nullptr, nullptr, N);
  k_bnfin<<<1, 128, 0, stream>>>(sum1, sq1, g1, be1, bnA1, bnB1, invN);
  k_bnrelub<<<4096, 256, 0, stream>>>(hpre_b, h1b, bnA1, bnB1, n4);

  // --- layer 2 aggregation ---
  k_gatherb<<<gablocks, 256, 0, stream>>>(h1b, slots, offs, meanb, N);

  // fused layer-2 + skip GEMM (shares self A-fragments; h1b read once)
  k_gemm<true><<<gmblocks, 256, 0, stream>>>(h1b, meanb, Wb2, Wb3, b2, b_skip,
                                             hpre_b, skip_b, sum2, sq2, sum3, sq3, N);
  k_bnfin<<<1, 128, 0, stream>>>(sum2, sq2, g2, be2, bnA2, bnB2, invN);
  k_bnfin<<<1, 128, 0, stream>>>(sum3, sq3, g3, be3, bnA3, bnB3, invN);

  k_final<<<4096, 256, 0, stream>>>(hpre_b, skip_b, out, bnA2, bnB2, bnA3, bnB3, n4);
}

// Round 3
// 396.510 us; speedup vs baseline: 1.1936x; 1.1936x over previous
//
#include <hip/hip_runtime.h>

#define D 128
#define PCHUNK 4096
#define SCAP 8192

typedef short bf16x8 __attribute__((ext_vector_type(8)));
typedef float f32x4 __attribute__((ext_vector_type(4)));

__device__ __forceinline__ ushort f2b(float f){
  unsigned u = __builtin_bit_cast(unsigned, f);
  u += 0x7fffu + ((u >> 16) & 1u);          // round-to-nearest-even
  return (ushort)(u >> 16);
}
__device__ __forceinline__ float b2f(ushort h){
  unsigned u = ((unsigned)h) << 16;
  return __builtin_bit_cast(float, u);
}

// ---------------- P0: coarse bucket histogram (bucket = dst>>8) ----------------
__global__ __launch_bounds__(256) void k_p0(const int* __restrict__ dst,
                                            int* __restrict__ bcnt, int E){
  __shared__ int h[512];
  for (int u=threadIdx.x; u<512; u+=256) h[u]=0;
  __syncthreads();
  for (long long i=(long long)blockIdx.x*256+threadIdx.x; i<E; i+=(long long)gridDim.x*256)
    atomicAdd(&h[dst[i]>>8], 1);
  __syncthreads();
  for (int u=threadIdx.x; u<512; u+=256) if (h[u]) atomicAdd(&bcnt[u], h[u]);
}

// ---------------- P1: scan buckets -> base & cursor ----------------
__global__ void k_bscan(const int* __restrict__ bcnt, int* __restrict__ bbase,
                        int* __restrict__ bcur, int nb, int E){
  __shared__ int sh[1024];
  int t = threadIdx.x;
  int v = (t<nb) ? bcnt[t] : 0;
  sh[t]=v; __syncthreads();
  for (int off=1; off<1024; off<<=1){
    int add = (t>=off)?sh[t-off]:0;
    __syncthreads();
    sh[t]+=add;
    __syncthreads();
  }
  if (t<nb){ int e=sh[t]-v; bbase[t]=e; bcur[t]=e; }
  if (t==nb) bbase[t]=E;
}

// ---------------- P2: LDS-binned partition of (src,dst) into buckets ----------------
__global__ __launch_bounds__(256) void k_part(const int* __restrict__ src,
        const int* __restrict__ dst, int* __restrict__ bcur,
        int2* __restrict__ pairs, int E){
  __shared__ int hist[512], offA[512], offB[512], gbase[512];
  __shared__ int sS[PCHUNK], sD[PCHUNK];
  const int t = threadIdx.x;
  const int base = blockIdx.x * PCHUNK;
  const int cnt = min(PCHUNK, E - base);
  for (int u=t; u<512; u+=256) hist[u]=0;
  __syncthreads();
  int rs[16], rd[16];
  #pragma unroll
  for (int j=0;j<16;j++){
    int li = j*256 + t;
    if (li < cnt){
      rs[j]=src[base+li]; rd[j]=dst[base+li];
      atomicAdd(&hist[rd[j]>>8],1);
    } else { rs[j]=0; rd[j]=-1; }
  }
  __syncthreads();
  int *cur=offA, *nxt=offB;
  for (int u=t; u<512; u+=256) cur[u]=hist[u];
  __syncthreads();
  for (int off=1; off<512; off<<=1){
    for (int u=t; u<512; u+=256) nxt[u] = cur[u] + ((u>=off)?cur[u-off]:0);
    __syncthreads();
    int* tmp=cur; cur=nxt; nxt=tmp;
  }
  for (int u=t; u<512; u+=256) nxt[u] = cur[u]-hist[u];
  __syncthreads();
  #pragma unroll
  for (int j=0;j<16;j++){
    if (j*256+t < cnt){
      int b = rd[j]>>8;
      int p = atomicAdd(&nxt[b],1);
      sS[p]=rs[j]; sD[p]=rd[j];
    }
  }
  __syncthreads();
  for (int u=t; u<512; u+=256){
    int c = hist[u];
    if (c>0) gbase[u] = atomicAdd(&bcur[u], c);
  }
  __syncthreads();
  #pragma unroll
  for (int j=0;j<16;j++){
    int idx = j*256+t;
    if (idx<cnt){
      int d = sD[idx]; int b = d>>8;
      int gpos = gbase[b] + (idx - (cur[b]-hist[b]));
      pairs[gpos] = make_int2(sS[idx], d);
    }
  }
}

// ---------------- P3: per-bucket exact counting sort -> slots + offs ----------------
__global__ __launch_bounds__(256) void k_sortb(const int2* __restrict__ pairs,
        const int* __restrict__ bbase, int* __restrict__ offs,
        int* __restrict__ slots, int N, int NB){
  __shared__ int nh[256], nc[256], sc[256];
  __shared__ int stage[SCAP];
  const int b = blockIdx.x, t = threadIdx.x;
  const int base = bbase[b];
  const int cnt  = bbase[b+1] - base;
  nh[t]=0; __syncthreads();
  for (int i=t;i<cnt;i+=256) atomicAdd(&nh[pairs[base+i].y & 255],1);
  __syncthreads();
  int v = nh[t];
  sc[t]=v; __syncthreads();
  for (int off=1; off<256; off<<=1){
    int add = (t>=off)?sc[t-off]:0;
    __syncthreads();
    sc[t]+=add;
    __syncthreads();
  }
  int excl = sc[t]-v;
  nc[t]=excl;
  int node = (b<<8)+t;
  if (node<N) offs[node]=base+excl;
  if (b==NB-1 && t==0) offs[N]=bbase[NB];
  __syncthreads();
  if (cnt<=SCAP){
    for (int i=t;i<cnt;i+=256){
      int2 p = pairs[base+i];
      int pos = atomicAdd(&nc[p.y & 255],1);
      stage[pos]=p.x;
    }
    __syncthreads();
    for (int i=t;i<cnt;i+=256) slots[base+i]=stage[i];
  } else {
    for (int i=t;i<cnt;i+=256){
      int2 p = pairs[base+i];
      int pos = atomicAdd(&nc[p.y & 255],1);
      slots[base+pos]=p.x;
    }
  }
}

// ---------------- f32 -> bf16 cast ----------------
__global__ __launch_bounds__(256) void k_xcast(const float* __restrict__ x,
                                               ushort* __restrict__ xb, long long n4){
  long long i = (long long)blockIdx.x*256 + threadIdx.x;
  const long long stride = (long long)gridDim.x*256;
  for (; i < n4; i += stride){
    float4 v = reinterpret_cast<const float4*>(x)[i];
    ushort4 o;
    o.x = f2b(v.x); o.y = f2b(v.y); o.z = f2b(v.z); o.w = f2b(v.w);
    reinterpret_cast<ushort4*>(xb)[i] = o;
  }
}

// ---------------- weight transpose+cast: Wb[c*K + k0 + k] = bf16(W[k][c]) ----------------
__global__ void k_wt(const float* __restrict__ W, ushort* __restrict__ Wb, int K, int k0){
  int idx = blockIdx.x*256 + threadIdx.x;   // 0..16383
  int k = idx >> 7, c = idx & 127;
  Wb[(size_t)c*K + k0 + k] = f2b(W[idx]);
}

// ---------------- gather-mean (bf16 in/out): 64 threads/node, pipelined 8-edge groups ----
__global__ __launch_bounds__(256) void k_gatherb(const ushort* __restrict__ Xb,
        const int* __restrict__ slots, const int* __restrict__ offs,
        ushort* __restrict__ meanb, int N){
  int node = blockIdx.x*4 + (threadIdx.x >> 6);
  int c2 = (threadIdx.x & 63) * 2;            // this lane's channel pair
  if (node >= N) return;
  const int beg = offs[node], end = offs[node+1];
  float sx0=0,sy0=0,sx1=0,sy1=0,sx2=0,sy2=0,sx3=0,sy3=0;
  int j = beg;
  // align to int4 boundary
  while (j < end && (j & 3)){
    unsigned u = *reinterpret_cast<const unsigned*>(&Xb[(size_t)slots[j]*D + c2]);
    sx0 += b2f((ushort)u); sy0 += b2f((ushort)(u>>16));
    ++j;
  }
  const int nfull = (end - j) >> 2;           // # of aligned 4-edge groups
  const int4* sp = reinterpret_cast<const int4*>(slots + j);

#define G8(ia, ib) { \
    unsigned u0 = *reinterpret_cast<const unsigned*>(&Xb[(size_t)(ia).x*D + c2]); \
    unsigned u1 = *reinterpret_cast<const unsigned*>(&Xb[(size_t)(ia).y*D + c2]); \
    unsigned u2 = *reinterpret_cast<const unsigned*>(&Xb[(size_t)(ia).z*D + c2]); \
    unsigned u3 = *reinterpret_cast<const unsigned*>(&Xb[(size_t)(ia).w*D + c2]); \
    unsigned u4 = *reinterpret_cast<const unsigned*>(&Xb[(size_t)(ib).x*D + c2]); \
    unsigned u5 = *reinterpret_cast<const unsigned*>(&Xb[(size_t)(ib).y*D + c2]); \
    unsigned u6 = *reinterpret_cast<const unsigned*>(&Xb[(size_t)(ib).z*D + c2]); \
    unsigned u7 = *reinterpret_cast<const unsigned*>(&Xb[(size_t)(ib).w*D + c2]); \
    sx0 += b2f((ushort)u0); sy0 += b2f((ushort)(u0>>16)); \
    sx1 += b2f((ushort)u1); sy1 += b2f((ushort)(u1>>16)); \
    sx2 += b2f((ushort)u2); sy2 += b2f((ushort)(u2>>16)); \
    sx3 += b2f((ushort)u3); sy3 += b2f((ushort)(u3>>16)); \
    sx0 += b2f((ushort)u4); sy0 += b2f((ushort)(u4>>16)); \
    sx1 += b2f((ushort)u5); sy1 += b2f((ushort)(u5>>16)); \
    sx2 += b2f((ushort)u6); sy2 += b2f((ushort)(u6>>16)); \
    sx3 += b2f((ushort)u7); sy3 += b2f((ushort)(u7>>16)); }

  int g = 0;
  if (nfull >= 2){
    int4 ia = sp[0], ib = sp[1];
    for (g = 2; g + 2 <= nfull; g += 2){
      int4 na = sp[g], nb = sp[g+1];     // next-group indices in flight during gathers
      G8(ia, ib);
      ia = na; ib = nb;
    }
    G8(ia, ib);
  }
  if (g < nfull){                        // one leftover 4-edge group
    int4 ia = sp[g];
    unsigned u0 = *reinterpret_cast<const unsigned*>(&Xb[(size_t)ia.x*D + c2]);
    unsigned u1 = *reinterpret_cast<const unsigned*>(&Xb[(size_t)ia.y*D + c2]);
    unsigned u2 = *reinterpret_cast<const unsigned*>(&Xb[(size_t)ia.z*D + c2]);
    unsigned u3 = *reinterpret_cast<const unsigned*>(&Xb[(size_t)ia.w*D + c2]);
    sx0 += b2f((ushort)u0); sy0 += b2f((ushort)(u0>>16));
    sx1 += b2f((ushort)u1); sy1 += b2f((ushort)(u1>>16));
    sx2 += b2f((ushort)u2); sy2 += b2f((ushort)(u2>>16));
    sx3 += b2f((ushort)u3); sy3 += b2f((ushort)(u3>>16));
  }
  j += 4*nfull;
  for (; j < end; ++j){
    unsigned u = *reinterpret_cast<const unsigned*>(&Xb[(size_t)slots[j]*D + c2]);
    sx0 += b2f((ushort)u); sy0 += b2f((ushort)(u>>16));
  }
#undef G8
  float deg = (float)(end - beg);
  float rc = deg > 0.f ? 1.0f/deg : 0.f;
  unsigned o = (unsigned)f2b((sx0+sx1+sx2+sx3)*rc)
             | ((unsigned)f2b((sy0+sy1+sy2+sy3)*rc) << 16);
  *reinterpret_cast<unsigned*>(&meanb[(size_t)node*D + c2]) = o;
}

// ---------------- MFMA GEMM: 64x128 tile, 4 waves (2x2), wave = 32x64 output ----------------
// C = [A0 | A1] @ Wb^T + bias (K=256), optional fused skip Ck = A0 @ Wk^T + biasK (K=128).
// Small accumulator (2x4 + 2x4 frags = 64 regs) keeps combined registers ~3 waves/SIMD
// -> 3 blocks/CU resident, so barrier drains of one block overlap other blocks' MFMAs.
template<bool SKIP>
__global__ __launch_bounds__(256) void k_mfma(
    const ushort* __restrict__ A0, const ushort* __restrict__ A1,
    const ushort* __restrict__ Wb, const ushort* __restrict__ Wk,
    const float* __restrict__ bias, const float* __restrict__ biasK,
    ushort* __restrict__ C, ushort* __restrict__ Ck,
    float* __restrict__ gS, float* __restrict__ gQ,
    float* __restrict__ gSK, float* __restrict__ gQK, int N)
{
  __shared__ ushort At[64][40];
  __shared__ ushort Wt[128][40];
  __shared__ ushort Wkt[SKIP ? 128*40 : 1];
  __shared__ float shS[128], shQ[128], shSK[SKIP?128:1], shQK[SKIP?128:1];
  const int tid = threadIdx.x;
  if (tid < 128){ shS[tid]=0.f; shQ[tid]=0.f; if (SKIP){ shSK[tid]=0.f; shQK[tid]=0.f; } }
  const int row0 = blockIdx.x * 64;
  const int lane = tid & 63, wid = tid >> 6;
  const int wr = wid >> 1, wc = wid & 1;
  const int lr = lane & 15, kq = lane >> 4;

  f32x4 acc[2][4], accK[SKIP?2:1][SKIP?4:1];
  #pragma unroll
  for (int m=0;m<2;m++)
    #pragma unroll
    for (int n=0;n<4;n++) acc[m][n] = (f32x4){0.f,0.f,0.f,0.f};
  if (SKIP){
    #pragma unroll
    for (int m=0;m<2;m++)
      #pragma unroll
      for (int n=0;n<4;n++) accK[m][n] = (f32x4){0.f,0.f,0.f,0.f};
  }

  const int srA = tid >> 2;               // 0..63 (A-tile row)
  const int s8A = (tid & 3) * 8;          // chunk within 32-wide K slice
  const int growA = row0 + srA;

  for (int t=0; t<8; ++t){
    const ushort* Asrc = (t>=4) ? A1 : A0;
    const int ka = (t & 3) * 32;
    const int kw = t * 32;
    __syncthreads();
    // stage A: 64 rows x 32 ch = 256 chunks, one per thread
    int4 va = make_int4(0,0,0,0);
    if (growA < N) va = *reinterpret_cast<const int4*>(&Asrc[(size_t)growA*D + ka + s8A]);
    *reinterpret_cast<int4*>(&At[srA][s8A]) = va;
    // stage W (and Wk while t<4): 128 rows x 32 ch = 512 chunks, two per thread
    #pragma unroll
    for (int jj=0; jj<2; ++jj){
      int idx = tid + 256*jj;
      int sr = idx >> 2, s8 = (idx & 3) * 8;
      *reinterpret_cast<int4*>(&Wt[sr][s8]) =
          *reinterpret_cast<const int4*>(&Wb[(size_t)sr*256 + kw + s8]);
      if (SKIP && t < 4)
        *reinterpret_cast<int4*>(&Wkt[sr*40 + s8]) =
            *reinterpret_cast<const int4*>(&Wk[(size_t)sr*128 + kw + s8]);
    }
    __syncthreads();
    bf16x8 af[2], bw[4];
    #pragma unroll
    for (int m=0;m<2;m++)
      af[m] = *reinterpret_cast<const bf16x8*>(&At[32*wr + 16*m + lr][kq*8]);
    #pragma unroll
    for (int n=0;n<4;n++)
      bw[n] = *reinterpret_cast<const bf16x8*>(&Wt[64*wc + 16*n + lr][kq*8]);
    #pragma unroll
    for (int m=0;m<2;m++)
      #pragma unroll
      for (int n=0;n<4;n++)
        acc[m][n] = __builtin_amdgcn_mfma_f32_16x16x32_bf16(af[m], bw[n], acc[m][n], 0, 0, 0);
    if (SKIP && t < 4){
      bf16x8 bk[4];
      #pragma unroll
      for (int n=0;n<4;n++)
        bk[n] = *reinterpret_cast<const bf16x8*>(&Wkt[(64*wc + 16*n + lr)*40 + kq*8]);
      #pragma unroll
      for (int m=0;m<2;m++)
        #pragma unroll
        for (int n=0;n<4;n++)
          accK[m][n] = __builtin_amdgcn_mfma_f32_16x16x32_bf16(af[m], bk[n], accK[m][n], 0, 0, 0);
    }
  }

  // epilogue
  float bv[4], bkv[4];
  #pragma unroll
  for (int n=0;n<4;n++){
    bv[n] = bias[64*wc + 16*n + lr];
    bkv[n] = SKIP ? biasK[64*wc + 16*n + lr] : 0.f;
  }
  float bs[4]={0,0,0,0}, bq[4]={0,0,0,0}, bsk[4]={0,0,0,0}, bqk[4]={0,0,0,0};
  #pragma unroll
  for (int m=0;m<2;m++){
    #pragma unroll
    for (int r=0;r<4;r++){
      int row = row0 + 32*wr + 16*m + kq*4 + r;
      if (row < N){
        #pragma unroll
        for (int n=0;n<4;n++){
          int col = 64*wc + 16*n + lr;
          float v = acc[m][n][r] + bv[n];
          C[(size_t)row*D + col] = f2b(v);
          bs[n] += v; bq[n] += v*v;
          if (SKIP){
            float u = accK[m][n][r] + bkv[n];
            Ck[(size_t)row*D + col] = f2b(u);
            bsk[n] += u; bqk[n] += u*u;
          }
        }
      }
    }
  }
  #pragma unroll
  for (int n=0;n<4;n++){
    int col = 64*wc + 16*n + lr;
    atomicAdd(&shS[col], bs[n]);
    atomicAdd(&shQ[col], bq[n]);
    if (SKIP){
      atomicAdd(&shSK[col], bsk[n]);
      atomicAdd(&shQK[col], bqk[n]);
    }
  }
  __syncthreads();
  if (tid < 128){
    unsafeAtomicAdd(&gS[tid], shS[tid]);
    unsafeAtomicAdd(&gQ[tid], shQ[tid]);
    if (SKIP){
      unsafeAtomicAdd(&gSK[tid], shSK[tid]);
      unsafeAtomicAdd(&gQK[tid], shQK[tid]);
    }
  }
}

// ---------------- BN finalize ----------------
__global__ void k_bnfin(const float* __restrict__ sum, const float* __restrict__ sq,
                        const float* __restrict__ g, const float* __restrict__ be,
                        float* __restrict__ bnA, float* __restrict__ bnB, float invN){
  int c = threadIdx.x;
  float m = sum[c]*invN;
  float v = sq[c]*invN - m*m;
  float a = g[c]*rsqrtf(fmaxf(v, 0.f) + 1e-5f);
  bnA[c] = a;
  bnB[c] = be[c] - m*a;
}

// ---------------- BN + ReLU, bf16 in -> bf16 out ----------------
__global__ __launch_bounds__(256) void k_bnrelub(const ushort* __restrict__ hpre,
      ushort* __restrict__ hb,
      const float* __restrict__ A, const float* __restrict__ Bp, long long n4){
  long long i = (long long)blockIdx.x*256 + threadIdx.x;
  const long long stride = (long long)gridDim.x*256;
  for (; i < n4; i += stride){
    int c = ((int)(i & 31)) << 2;
    float4 a = *reinterpret_cast<const float4*>(A + c);
    float4 b = *reinterpret_cast<const float4*>(Bp + c);
    ushort4 hv = reinterpret_cast<const ushort4*>(hpre)[i];
    ushort4 o;
    o.x = f2b(fmaxf(a.x*b2f(hv.x) + b.x, 0.f));
    o.y = f2b(fmaxf(a.y*b2f(hv.y) + b.y, 0.f));
    o.z = f2b(fmaxf(a.z*b2f(hv.z) + b.z, 0.f));
    o.w = f2b(fmaxf(a.w*b2f(hv.w) + b.w, 0.f));
    reinterpret_cast<ushort4*>(hb)[i] = o;
  }
}

// ---------------- final: out = relu(bn2(h2) + bn3(skip)), f32 out ----------------
__global__ __launch_bounds__(256) void k_final(const ushort* __restrict__ h2,
      const ushort* __restrict__ sk, float* __restrict__ out,
      const float* __restrict__ A2, const float* __restrict__ B2,
      const float* __restrict__ A3, const float* __restrict__ B3, long long n4){
  long long i = (long long)blockIdx.x*256 + threadIdx.x;
  const long long stride = (long long)gridDim.x*256;
  for (; i < n4; i += stride){
    int c = ((int)(i & 31)) << 2;
    float4 a2 = *reinterpret_cast<const float4*>(A2 + c);
    float4 b2 = *reinterpret_cast<const float4*>(B2 + c);
    float4 a3 = *reinterpret_cast<const float4*>(A3 + c);
    float4 b3 = *reinterpret_cast<const float4*>(B3 + c);
    ushort4 h = reinterpret_cast<const ushort4*>(h2)[i];
    ushort4 s = reinterpret_cast<const ushort4*>(sk)[i];
    float4 v;
    v.x = fmaxf(a2.x*b2f(h.x) + b2.x + a3.x*b2f(s.x) + b3.x, 0.f);
    v.y = fmaxf(a2.y*b2f(h.y) + b2.y + a3.y*b2f(s.y) + b3.y, 0.f);
    v.z = fmaxf(a2.z*b2f(h.z) + b2.z + a3.z*b2f(s.z) + b3.z, 0.f);
    v.w = fmaxf(a2.w*b2f(h.w) + b2.w + a3.w*b2f(s.w) + b3.w, 0.f);
    reinterpret_cast<float4*>(out)[i] = v;
  }
}

extern "C" void kernel_launch(void* const* d_in, const int* in_sizes, int n_in,
                              void* d_out, int out_size, void* d_ws, size_t ws_size,
                              hipStream_t stream) {
  const float* x        = (const float*)d_in[0];
  const int*   src      = (const int*)  d_in[1];
  const int*   dst      = (const int*)  d_in[2];
  const float* w_self1  = (const float*)d_in[3];
  const float* w_neigh1 = (const float*)d_in[4];
  const float* b1       = (const float*)d_in[5];
  const float* w_self2  = (const float*)d_in[6];
  const float* w_neigh2 = (const float*)d_in[7];
  const float* b2       = (const float*)d_in[8];
  const float* w_skip   = (const float*)d_in[9];
  const float* b_skip   = (const float*)d_in[10];
  const float* g1       = (const float*)d_in[11];
  const float* be1      = (const float*)d_in[12];
  const float* g2       = (const float*)d_in[13];
  const float* be2      = (const float*)d_in[14];
  const float* g3       = (const float*)d_in[15];
  const float* be3      = (const float*)d_in[16];
  (void)n_in; (void)ws_size;

  const int N = in_sizes[0] / D;
  const int E = in_sizes[1];
  const int NB = (N + 255) >> 8;
  float* out = (float*)d_out;

  // ---- workspace layout ----
  char* p = (char*)d_ws;
  const size_t nd2 = (((size_t)N * D * 2) + 255) / 256 * 256;   // bf16 [N][D]
  ushort* meanb  = (ushort*)p; p += nd2;
  ushort* h1b    = (ushort*)p; p += nd2;
  ushort* hpre_b = (ushort*)p; p += nd2;     // h1pre, then h2pre (aliased)
  ushort* skip_b = (ushort*)p; p += nd2;
  ushort* Wb1    = (ushort*)p; p += 256*128*2;
  ushort* Wb2    = (ushort*)p; p += 256*128*2;
  ushort* Wb3    = (ushort*)p; p += 128*128*2;
  int*    offs   = (int*)p;   p += (((size_t)(N+1)*4) + 255) / 256 * 256;
  int*    bcnt   = (int*)p;   p += 2304;
  float*  st     = (float*)p; p += 1536*sizeof(float);
  int*    bbase  = (int*)p;   p += 2304;
  int*    bcur   = (int*)p;   p += 2048;
  float *sum1=st,      *sq1=st+128,  *sum2=st+256, *sq2=st+384, *sum3=st+512, *sq3=st+640;
  float *bnA1=st+768,  *bnB1=st+896, *bnA2=st+1024,*bnB2=st+1152,*bnA3=st+1280,*bnB3=st+1408;

  // scratch in d_out (dead before k_final rewrites all of d_out)
  const size_t slpad = (((size_t)E*4) + 255) / 256 * 256;
  const size_t xbpad = (((size_t)N*D*2) + 255) / 256 * 256;
  int*    slots = (int*)d_out;
  ushort* xb    = (ushort*)((char*)d_out + slpad);
  int2*   pairs = (int2*)((char*)d_out + slpad + xbpad);

  hipMemsetAsync(bcnt, 0, 2304 + 1536*sizeof(float), stream);

  const long long n4 = (long long)N * D / 4;

  // --- casts / weight prep ---
  k_xcast<<<2048, 256, 0, stream>>>(x, xb, n4);
  k_wt<<<64, 256, 0, stream>>>(w_self1,  Wb1, 256, 0);
  k_wt<<<64, 256, 0, stream>>>(w_neigh1, Wb1, 256, 128);
  k_wt<<<64, 256, 0, stream>>>(w_self2,  Wb2, 256, 0);
  k_wt<<<64, 256, 0, stream>>>(w_neigh2, Wb2, 256, 128);
  k_wt<<<64, 256, 0, stream>>>(w_skip,   Wb3, 128, 0);

  // --- CSR build via 2-level counting sort ---
  k_p0<<<1024, 256, 0, stream>>>(dst, bcnt, E);
  k_bscan<<<1, 1024, 0, stream>>>(bcnt, bbase, bcur, NB, E);
  k_part<<<(E + PCHUNK - 1)/PCHUNK, 256, 0, stream>>>(src, dst, bcur, pairs, E);
  k_sortb<<<NB, 256, 0, stream>>>(pairs, bbase, offs, slots, N, NB);

  const int gablocks = (N + 3) / 4;
  const int gmblocks = (N + 63) / 64;
  const float invN = 1.0f / (float)N;

  // --- layer 1 ---
  k_gatherb<<<gablocks, 256, 0, stream>>>(xb, slots, offs, meanb, N);
  k_mfma<false><<<gmblocks, 256, 0, stream>>>(xb, meanb, Wb1, nullptr, b1, nullptr,
                                              hpre_b, nullptr, sum1, sq1, nullptr, nullptr, N);
  k_bnfin<<<1, 128, 0, stream>>>(sum1, sq1, g1, be1, bnA1, bnB1, invN);
  k_bnrelub<<<4096, 256, 0, stream>>>(hpre_b, h1b, bnA1, bnB1, n4);

  // --- layer 2 aggregation ---
  k_gatherb<<<gablocks, 256, 0, stream>>>(h1b, slots, offs, meanb, N);

  // fused layer-2 + skip GEMM (shares A fragments; h1b read once)
  k_mfma<true><<<gmblocks, 256, 0, stream>>>(h1b, meanb, Wb2, Wb3, b2, b_skip,
                                             hpre_b, skip_b, sum2, sq2, sum3, sq3, N);
  k_bnfin<<<1, 128, 0, stream>>>(sum2, sq2, g2, be2, bnA2, bnB2, invN);
  k_bnfin<<<1, 128, 0, stream>>>(sum3, sq3, g3, be3, bnA3, bnB3, invN);

  k_final<<<4096, 256, 0, stream>>>(hpre_b, skip_b, out, bnA2, bnB2, bnA3, bnB3, n4);
}

// Round 4
// 396.034 us; speedup vs baseline: 1.1951x; 1.0012x over previous
//
#include <hip/hip_runtime.h>

#define D 128
#define PCHUNK 4096
#define SCAP 8192

typedef short bf16x8 __attribute__((ext_vector_type(8)));
typedef float f32x4 __attribute__((ext_vector_type(4)));

__device__ __forceinline__ ushort f2b(float f){
  unsigned u = __builtin_bit_cast(unsigned, f);
  u += 0x7fffu + ((u >> 16) & 1u);          // round-to-nearest-even
  return (ushort)(u >> 16);
}
__device__ __forceinline__ float b2f(ushort h){
  unsigned u = ((unsigned)h) << 16;
  return __builtin_bit_cast(float, u);
}

// ---------------- P0: coarse bucket histogram (bucket = dst>>8) ----------------
__global__ __launch_bounds__(256) void k_p0(const int* __restrict__ dst,
                                            int* __restrict__ bcnt, int E){
  __shared__ int h[512];
  for (int u=threadIdx.x; u<512; u+=256) h[u]=0;
  __syncthreads();
  for (long long i=(long long)blockIdx.x*256+threadIdx.x; i<E; i+=(long long)gridDim.x*256)
    atomicAdd(&h[dst[i]>>8], 1);
  __syncthreads();
  for (int u=threadIdx.x; u<512; u+=256) if (h[u]) atomicAdd(&bcnt[u], h[u]);
}

// ---------------- P1: scan buckets -> base & cursor ----------------
__global__ void k_bscan(const int* __restrict__ bcnt, int* __restrict__ bbase,
                        int* __restrict__ bcur, int nb, int E){
  __shared__ int sh[1024];
  int t = threadIdx.x;
  int v = (t<nb) ? bcnt[t] : 0;
  sh[t]=v; __syncthreads();
  for (int off=1; off<1024; off<<=1){
    int add = (t>=off)?sh[t-off]:0;
    __syncthreads();
    sh[t]+=add;
    __syncthreads();
  }
  if (t<nb){ int e=sh[t]-v; bbase[t]=e; bcur[t]=e; }
  if (t==nb) bbase[t]=E;
}

// ---------------- P2: LDS-binned partition of (src,dst) into buckets ----------------
__global__ __launch_bounds__(256) void k_part(const int* __restrict__ src,
        const int* __restrict__ dst, int* __restrict__ bcur,
        int2* __restrict__ pairs, int E){
  __shared__ int hist[512], offA[512], offB[512], gbase[512];
  __shared__ int sS[PCHUNK], sD[PCHUNK];
  const int t = threadIdx.x;
  const int base = blockIdx.x * PCHUNK;
  const int cnt = min(PCHUNK, E - base);
  for (int u=t; u<512; u+=256) hist[u]=0;
  __syncthreads();
  int rs[16], rd[16];
  #pragma unroll
  for (int j=0;j<16;j++){
    int li = j*256 + t;
    if (li < cnt){
      rs[j]=src[base+li]; rd[j]=dst[base+li];
      atomicAdd(&hist[rd[j]>>8],1);
    } else { rs[j]=0; rd[j]=-1; }
  }
  __syncthreads();
  int *cur=offA, *nxt=offB;
  for (int u=t; u<512; u+=256) cur[u]=hist[u];
  __syncthreads();
  for (int off=1; off<512; off<<=1){
    for (int u=t; u<512; u+=256) nxt[u] = cur[u] + ((u>=off)?cur[u-off]:0);
    __syncthreads();
    int* tmp=cur; cur=nxt; nxt=tmp;
  }
  for (int u=t; u<512; u+=256) nxt[u] = cur[u]-hist[u];
  __syncthreads();
  #pragma unroll
  for (int j=0;j<16;j++){
    if (j*256+t < cnt){
      int b = rd[j]>>8;
      int p = atomicAdd(&nxt[b],1);
      sS[p]=rs[j]; sD[p]=rd[j];
    }
  }
  __syncthreads();
  for (int u=t; u<512; u+=256){
    int c = hist[u];
    if (c>0) gbase[u] = atomicAdd(&bcur[u], c);
  }
  __syncthreads();
  #pragma unroll
  for (int j=0;j<16;j++){
    int idx = j*256+t;
    if (idx<cnt){
      int d = sD[idx]; int b = d>>8;
      int gpos = gbase[b] + (idx - (cur[b]-hist[b]));
      pairs[gpos] = make_int2(sS[idx], d);
    }
  }
}

// ---------------- P3: per-bucket exact counting sort -> slots + offs ----------------
__global__ __launch_bounds__(256) void k_sortb(const int2* __restrict__ pairs,
        const int* __restrict__ bbase, int* __restrict__ offs,
        int* __restrict__ slots, int N, int NB){
  __shared__ int nh[256], nc[256], sc[256];
  __shared__ int stage[SCAP];
  const int b = blockIdx.x, t = threadIdx.x;
  const int base = bbase[b];
  const int cnt  = bbase[b+1] - base;
  nh[t]=0; __syncthreads();
  for (int i=t;i<cnt;i+=256) atomicAdd(&nh[pairs[base+i].y & 255],1);
  __syncthreads();
  int v = nh[t];
  sc[t]=v; __syncthreads();
  for (int off=1; off<256; off<<=1){
    int add = (t>=off)?sc[t-off]:0;
    __syncthreads();
    sc[t]+=add;
    __syncthreads();
  }
  int excl = sc[t]-v;
  nc[t]=excl;
  int node = (b<<8)+t;
  if (node<N) offs[node]=base+excl;
  if (b==NB-1 && t==0) offs[N]=bbase[NB];
  __syncthreads();
  if (cnt<=SCAP){
    for (int i=t;i<cnt;i+=256){
      int2 p = pairs[base+i];
      int pos = atomicAdd(&nc[p.y & 255],1);
      stage[pos]=p.x;
    }
    __syncthreads();
    for (int i=t;i<cnt;i+=256) slots[base+i]=stage[i];
  } else {
    for (int i=t;i<cnt;i+=256){
      int2 p = pairs[base+i];
      int pos = atomicAdd(&nc[p.y & 255],1);
      slots[base+pos]=p.x;
    }
  }
}

// ---------------- f32 -> bf16 cast ----------------
__global__ __launch_bounds__(256) void k_xcast(const float* __restrict__ x,
                                               ushort* __restrict__ xb, long long n4){
  long long i = (long long)blockIdx.x*256 + threadIdx.x;
  const long long stride = (long long)gridDim.x*256;
  for (; i < n4; i += stride){
    float4 v = reinterpret_cast<const float4*>(x)[i];
    ushort4 o;
    o.x = f2b(v.x); o.y = f2b(v.y); o.z = f2b(v.z); o.w = f2b(v.w);
    reinterpret_cast<ushort4*>(xb)[i] = o;
  }
}

// ---------------- weight transpose+cast: Wb[c*K + k0 + k] = bf16(W[k][c]) ----------------
__global__ void k_wt(const float* __restrict__ W, ushort* __restrict__ Wb, int K, int k0){
  int idx = blockIdx.x*256 + threadIdx.x;   // 0..16383
  int k = idx >> 7, c = idx & 127;
  Wb[(size_t)c*K + k0 + k] = f2b(W[idx]);
}

// ---------------- gather-mean (bf16 in/out): 64 threads/node, pipelined 8-edge groups ----
__global__ __launch_bounds__(256) void k_gatherb(const ushort* __restrict__ Xb,
        const int* __restrict__ slots, const int* __restrict__ offs,
        ushort* __restrict__ meanb, int N){
  int node = blockIdx.x*4 + (threadIdx.x >> 6);
  int c2 = (threadIdx.x & 63) * 2;            // this lane's channel pair
  if (node >= N) return;
  const int beg = offs[node], end = offs[node+1];
  float sx0=0,sy0=0,sx1=0,sy1=0,sx2=0,sy2=0,sx3=0,sy3=0;
  int j = beg;
  // align to int4 boundary
  while (j < end && (j & 3)){
    unsigned u = *reinterpret_cast<const unsigned*>(&Xb[(size_t)slots[j]*D + c2]);
    sx0 += b2f((ushort)u); sy0 += b2f((ushort)(u>>16));
    ++j;
  }
  const int nfull = (end - j) >> 2;           // # of aligned 4-edge groups
  const int4* sp = reinterpret_cast<const int4*>(slots + j);

#define G8(ia, ib) { \
    unsigned u0 = *reinterpret_cast<const unsigned*>(&Xb[(size_t)(ia).x*D + c2]); \
    unsigned u1 = *reinterpret_cast<const unsigned*>(&Xb[(size_t)(ia).y*D + c2]); \
    unsigned u2 = *reinterpret_cast<const unsigned*>(&Xb[(size_t)(ia).z*D + c2]); \
    unsigned u3 = *reinterpret_cast<const unsigned*>(&Xb[(size_t)(ia).w*D + c2]); \
    unsigned u4 = *reinterpret_cast<const unsigned*>(&Xb[(size_t)(ib).x*D + c2]); \
    unsigned u5 = *reinterpret_cast<const unsigned*>(&Xb[(size_t)(ib).y*D + c2]); \
    unsigned u6 = *reinterpret_cast<const unsigned*>(&Xb[(size_t)(ib).z*D + c2]); \
    unsigned u7 = *reinterpret_cast<const unsigned*>(&Xb[(size_t)(ib).w*D + c2]); \
    sx0 += b2f((ushort)u0); sy0 += b2f((ushort)(u0>>16)); \
    sx1 += b2f((ushort)u1); sy1 += b2f((ushort)(u1>>16)); \
    sx2 += b2f((ushort)u2); sy2 += b2f((ushort)(u2>>16)); \
    sx3 += b2f((ushort)u3); sy3 += b2f((ushort)(u3>>16)); \
    sx0 += b2f((ushort)u4); sy0 += b2f((ushort)(u4>>16)); \
    sx1 += b2f((ushort)u5); sy1 += b2f((ushort)(u5>>16)); \
    sx2 += b2f((ushort)u6); sy2 += b2f((ushort)(u6>>16)); \
    sx3 += b2f((ushort)u7); sy3 += b2f((ushort)(u7>>16)); }

  int g = 0;
  if (nfull >= 2){
    int4 ia = sp[0], ib = sp[1];
    for (g = 2; g + 2 <= nfull; g += 2){
      int4 na = sp[g], nb = sp[g+1];     // next-group indices in flight during gathers
      G8(ia, ib);
      ia = na; ib = nb;
    }
    G8(ia, ib);
  }
  if (g < nfull){                        // one leftover 4-edge group
    int4 ia = sp[g];
    unsigned u0 = *reinterpret_cast<const unsigned*>(&Xb[(size_t)ia.x*D + c2]);
    unsigned u1 = *reinterpret_cast<const unsigned*>(&Xb[(size_t)ia.y*D + c2]);
    unsigned u2 = *reinterpret_cast<const unsigned*>(&Xb[(size_t)ia.z*D + c2]);
    unsigned u3 = *reinterpret_cast<const unsigned*>(&Xb[(size_t)ia.w*D + c2]);
    sx0 += b2f((ushort)u0); sy0 += b2f((ushort)(u0>>16));
    sx1 += b2f((ushort)u1); sy1 += b2f((ushort)(u1>>16));
    sx2 += b2f((ushort)u2); sy2 += b2f((ushort)(u2>>16));
    sx3 += b2f((ushort)u3); sy3 += b2f((ushort)(u3>>16));
  }
  j += 4*nfull;
  for (; j < end; ++j){
    unsigned u = *reinterpret_cast<const unsigned*>(&Xb[(size_t)slots[j]*D + c2]);
    sx0 += b2f((ushort)u); sy0 += b2f((ushort)(u>>16));
  }
#undef G8
  float deg = (float)(end - beg);
  float rc = deg > 0.f ? 1.0f/deg : 0.f;
  unsigned o = (unsigned)f2b((sx0+sx1+sx2+sx3)*rc)
             | ((unsigned)f2b((sy0+sy1+sy2+sy3)*rc) << 16);
  *reinterpret_cast<unsigned*>(&meanb[(size_t)node*D + c2]) = o;
}

// ---------------- 2-phase pipelined MFMA GEMM: 64x128 tile, 4 waves (2x2) ----------------
// C = [A0 | A1] @ Wb^T + bias (K=256), optional fused skip Ck = A0 @ Wk^T + biasK (K=128).
// Double-buffered LDS; per k-step: ds_read frags[p] -> issue global loads for t+2 ->
// MFMA(t) -> ds_write buf[q] (regs of t+1, compiler inserts counted vmcnt) ->
// lgkmcnt(0) + RAW s_barrier (no vmcnt drain: prefetch stays in flight across barrier).
template<bool SKIP>
__global__ __launch_bounds__(256, 3) void k_mfma(
    const ushort* __restrict__ A0, const ushort* __restrict__ A1,
    const ushort* __restrict__ Wb, const ushort* __restrict__ Wk,
    const float* __restrict__ bias, const float* __restrict__ biasK,
    ushort* __restrict__ C, ushort* __restrict__ Ck,
    float* __restrict__ gS, float* __restrict__ gQ,
    float* __restrict__ gSK, float* __restrict__ gQK, int N)
{
  __shared__ ushort At[2][64][40];
  __shared__ ushort Wt[2][128][40];
  __shared__ ushort Wkt[SKIP ? 2*128*40 : 1];
  __shared__ float shS[128], shQ[128], shSK[SKIP?128:1], shQK[SKIP?128:1];
  const int tid = threadIdx.x;
  if (tid < 128){ shS[tid]=0.f; shQ[tid]=0.f; if (SKIP){ shSK[tid]=0.f; shQK[tid]=0.f; } }
  const int row0 = blockIdx.x * 64;
  const int lane = tid & 63, wid = tid >> 6;
  const int wr = wid >> 1, wc = wid & 1;
  const int lr = lane & 15, kq = lane >> 4;

  // staging geometry: A = 256 chunks (64 rows x 4), one per thread;
  // W/Wk = 512 chunks (128 rows x 4), two per thread (rows srW and srW+64).
  const int srA = tid >> 2, s8A = (tid & 3) * 8;
  int growA = row0 + srA; if (growA >= N) growA = N - 1;   // clamp; epilogue guards
  const size_t abase = (size_t)growA * D + s8A;
  const int srW = tid >> 2, s8W = (tid & 3) * 8;

  int4 va[2], vw[2][2], vk[2][2];

#define LOADS(S, T) { \
    const ushort* As_ = ((T) >= 4) ? A1 : A0; \
    va[S] = *reinterpret_cast<const int4*>(&As_[abase + ((T)&3)*32]); \
    vw[S][0] = *reinterpret_cast<const int4*>(&Wb[(size_t)srW*256 + (T)*32 + s8W]); \
    vw[S][1] = *reinterpret_cast<const int4*>(&Wb[(size_t)(srW+64)*256 + (T)*32 + s8W]); \
    if (SKIP && (T) < 4){ \
      vk[S][0] = *reinterpret_cast<const int4*>(&Wk[(size_t)srW*128 + (T)*32 + s8W]); \
      vk[S][1] = *reinterpret_cast<const int4*>(&Wk[(size_t)(srW+64)*128 + (T)*32 + s8W]); \
    } }

#define WRITES(S, T) { \
    *reinterpret_cast<int4*>(&At[S][srA][s8A]) = va[S]; \
    *reinterpret_cast<int4*>(&Wt[S][srW][s8W]) = vw[S][0]; \
    *reinterpret_cast<int4*>(&Wt[S][srW+64][s8W]) = vw[S][1]; \
    if (SKIP && (T) < 4){ \
      *reinterpret_cast<int4*>(&Wkt[((S)*128 + srW)*40 + s8W]) = vk[S][0]; \
      *reinterpret_cast<int4*>(&Wkt[((S)*128 + srW + 64)*40 + s8W]) = vk[S][1]; \
    } }

  f32x4 acc[2][4], accK[SKIP?2:1][SKIP?4:1];
  #pragma unroll
  for (int m=0;m<2;m++)
    #pragma unroll
    for (int n=0;n<4;n++) acc[m][n] = (f32x4){0.f,0.f,0.f,0.f};
  if (SKIP){
    #pragma unroll
    for (int m=0;m<2;m++)
      #pragma unroll
      for (int n=0;n<4;n++) accK[m][n] = (f32x4){0.f,0.f,0.f,0.f};
  }

  // prologue: fill buf0 (t=0), start loads for t=1
  LOADS(0, 0);
  WRITES(0, 0);                       // compiler inserts vmcnt wait for set 0
  LOADS(1, 1);
  asm volatile("s_waitcnt lgkmcnt(0)" ::: "memory");
  __builtin_amdgcn_s_barrier();
  __builtin_amdgcn_sched_barrier(0);

  #pragma unroll
  for (int t=0; t<8; ++t){
    const int p = t & 1, q = p ^ 1;
    bf16x8 af[2], bw[4], bk[SKIP?4:1];
    #pragma unroll
    for (int m=0;m<2;m++)
      af[m] = *reinterpret_cast<const bf16x8*>(&At[p][32*wr + 16*m + lr][kq*8]);
    #pragma unroll
    for (int n=0;n<4;n++)
      bw[n] = *reinterpret_cast<const bf16x8*>(&Wt[p][64*wc + 16*n + lr][kq*8]);
    if (SKIP && t < 4){
      #pragma unroll
      for (int n=0;n<4;n++)
        bk[n] = *reinterpret_cast<const bf16x8*>(&Wkt[((size_t)p*128 + 64*wc + 16*n + lr)*40 + kq*8]);
    }
    if (t+2 < 8) LOADS(p, t+2);       // in flight across MFMA and the raw barrier
    #pragma unroll
    for (int m=0;m<2;m++)
      #pragma unroll
      for (int n=0;n<4;n++)
        acc[m][n] = __builtin_amdgcn_mfma_f32_16x16x32_bf16(af[m], bw[n], acc[m][n], 0, 0, 0);
    if (SKIP && t < 4){
      #pragma unroll
      for (int m=0;m<2;m++)
        #pragma unroll
        for (int n=0;n<4;n++)
          accK[m][n] = __builtin_amdgcn_mfma_f32_16x16x32_bf16(af[m], bk[n], accK[m][n], 0, 0, 0);
    }
    if (t+1 < 8){
      WRITES(q, t+1);                 // counted vmcnt wait on set q only
      asm volatile("s_waitcnt lgkmcnt(0)" ::: "memory");
      __builtin_amdgcn_s_barrier();   // raw barrier: no vmcnt(0) drain
      __builtin_amdgcn_sched_barrier(0);
    }
  }
#undef LOADS
#undef WRITES

  // epilogue
  float bv[4], bkv[4];
  #pragma unroll
  for (int n=0;n<4;n++){
    bv[n] = bias[64*wc + 16*n + lr];
    bkv[n] = SKIP ? biasK[64*wc + 16*n + lr] : 0.f;
  }
  float bs[4]={0,0,0,0}, bq[4]={0,0,0,0}, bsk[4]={0,0,0,0}, bqk[4]={0,0,0,0};
  #pragma unroll
  for (int m=0;m<2;m++){
    #pragma unroll
    for (int r=0;r<4;r++){
      int row = row0 + 32*wr + 16*m + kq*4 + r;
      if (row < N){
        #pragma unroll
        for (int n=0;n<4;n++){
          int col = 64*wc + 16*n + lr;
          float v = acc[m][n][r] + bv[n];
          C[(size_t)row*D + col] = f2b(v);
          bs[n] += v; bq[n] += v*v;
          if (SKIP){
            float u = accK[m][n][r] + bkv[n];
            Ck[(size_t)row*D + col] = f2b(u);
            bsk[n] += u; bqk[n] += u*u;
          }
        }
      }
    }
  }
  #pragma unroll
  for (int n=0;n<4;n++){
    int col = 64*wc + 16*n + lr;
    atomicAdd(&shS[col], bs[n]);
    atomicAdd(&shQ[col], bq[n]);
    if (SKIP){
      atomicAdd(&shSK[col], bsk[n]);
      atomicAdd(&shQK[col], bqk[n]);
    }
  }
  __syncthreads();
  if (tid < 128){
    unsafeAtomicAdd(&gS[tid], shS[tid]);
    unsafeAtomicAdd(&gQ[tid], shQ[tid]);
    if (SKIP){
      unsafeAtomicAdd(&gSK[tid], shSK[tid]);
      unsafeAtomicAdd(&gQK[tid], shQK[tid]);
    }
  }
}

// ---------------- BN finalize ----------------
__global__ void k_bnfin(const float* __restrict__ sum, const float* __restrict__ sq,
                        const float* __restrict__ g, const float* __restrict__ be,
                        float* __restrict__ bnA, float* __restrict__ bnB, float invN){
  int c = threadIdx.x;
  float m = sum[c]*invN;
  float v = sq[c]*invN - m*m;
  float a = g[c]*rsqrtf(fmaxf(v, 0.f) + 1e-5f);
  bnA[c] = a;
  bnB[c] = be[c] - m*a;
}

// ---------------- BN + ReLU, bf16 in -> bf16 out ----------------
__global__ __launch_bounds__(256) void k_bnrelub(const ushort* __restrict__ hpre,
      ushort* __restrict__ hb,
      const float* __restrict__ A, const float* __restrict__ Bp, long long n4){
  long long i = (long long)blockIdx.x*256 + threadIdx.x;
  const long long stride = (long long)gridDim.x*256;
  for (; i < n4; i += stride){
    int c = ((int)(i & 31)) << 2;
    float4 a = *reinterpret_cast<const float4*>(A + c);
    float4 b = *reinterpret_cast<const float4*>(Bp + c);
    ushort4 hv = reinterpret_cast<const ushort4*>(hpre)[i];
    ushort4 o;
    o.x = f2b(fmaxf(a.x*b2f(hv.x) + b.x, 0.f));
    o.y = f2b(fmaxf(a.y*b2f(hv.y) + b.y, 0.f));
    o.z = f2b(fmaxf(a.z*b2f(hv.z) + b.z, 0.f));
    o.w = f2b(fmaxf(a.w*b2f(hv.w) + b.w, 0.f));
    reinterpret_cast<ushort4*>(hb)[i] = o;
  }
}

// ---------------- final: out = relu(bn2(h2) + bn3(skip)), f32 out ----------------
__global__ __launch_bounds__(256) void k_final(const ushort* __restrict__ h2,
      const ushort* __restrict__ sk, float* __restrict__ out,
      const float* __restrict__ A2, const float* __restrict__ B2,
      const float* __restrict__ A3, const float* __restrict__ B3, long long n4){
  long long i = (long long)blockIdx.x*256 + threadIdx.x;
  const long long stride = (long long)gridDim.x*256;
  for (; i < n4; i += stride){
    int c = ((int)(i & 31)) << 2;
    float4 a2 = *reinterpret_cast<const float4*>(A2 + c);
    float4 b2 = *reinterpret_cast<const float4*>(B2 + c);
    float4 a3 = *reinterpret_cast<const float4*>(A3 + c);
    float4 b3 = *reinterpret_cast<const float4*>(B3 + c);
    ushort4 h = reinterpret_cast<const ushort4*>(h2)[i];
    ushort4 s = reinterpret_cast<const ushort4*>(sk)[i];
    float4 v;
    v.x = fmaxf(a2.x*b2f(h.x) + b2.x + a3.x*b2f(s.x) + b3.x, 0.f);
    v.y = fmaxf(a2.y*b2f(h.y) + b2.y + a3.y*b2f(s.y) + b3.y, 0.f);
    v.z = fmaxf(a2.z*b2f(h.z) + b2.z + a3.z*b2f(s.z) + b3.z, 0.f);
    v.w = fmaxf(a2.w*b2f(h.w) + b2.w + a3.w*b2f(s.w) + b3.w, 0.f);
    reinterpret_cast<float4*>(out)[i] = v;
  }
}

extern "C" void kernel_launch(void* const* d_in, const int* in_sizes, int n_in,
                              void* d_out, int out_size, void* d_ws, size_t ws_size,
                              hipStream_t stream) {
  const float* x        = (const float*)d_in[0];
  const int*   src      = (const int*)  d_in[1];
  const int*   dst      = (const int*)  d_in[2];
  const float* w_self1  = (const float*)d_in[3];
  const float* w_neigh1 = (const float*)d_in[4];
  const float* b1       = (const float*)d_in[5];
  const float* w_self2  = (const float*)d_in[6];
  const float* w_neigh2 = (const float*)d_in[7];
  const float* b2       = (const float*)d_in[8];
  const float* w_skip   = (const float*)d_in[9];
  const float* b_skip   = (const float*)d_in[10];
  const float* g1       = (const float*)d_in[11];
  const float* be1      = (const float*)d_in[12];
  const float* g2       = (const float*)d_in[13];
  const float* be2      = (const float*)d_in[14];
  const float* g3       = (const float*)d_in[15];
  const float* be3      = (const float*)d_in[16];
  (void)n_in; (void)ws_size;

  const int N = in_sizes[0] / D;
  const int E = in_sizes[1];
  const int NB = (N + 255) >> 8;
  float* out = (float*)d_out;

  // ---- workspace layout ----
  char* p = (char*)d_ws;
  const size_t nd2 = (((size_t)N * D * 2) + 255) / 256 * 256;   // bf16 [N][D]
  ushort* meanb  = (ushort*)p; p += nd2;
  ushort* h1b    = (ushort*)p; p += nd2;
  ushort* hpre_b = (ushort*)p; p += nd2;     // h1pre, then h2pre (aliased)
  ushort* skip_b = (ushort*)p; p += nd2;
  ushort* Wb1    = (ushort*)p; p += 256*128*2;
  ushort* Wb2    = (ushort*)p; p += 256*128*2;
  ushort* Wb3    = (ushort*)p; p += 128*128*2;
  int*    offs   = (int*)p;   p += (((size_t)(N+1)*4) + 255) / 256 * 256;
  int*    bcnt   = (int*)p;   p += 2304;
  float*  st     = (float*)p; p += 1536*sizeof(float);
  int*    bbase  = (int*)p;   p += 2304;
  int*    bcur   = (int*)p;   p += 2048;
  float *sum1=st,      *sq1=st+128,  *sum2=st+256, *sq2=st+384, *sum3=st+512, *sq3=st+640;
  float *bnA1=st+768,  *bnB1=st+896, *bnA2=st+1024,*bnB2=st+1152,*bnA3=st+1280,*bnB3=st+1408;

  // scratch in d_out (dead before k_final rewrites all of d_out)
  const size_t slpad = (((size_t)E*4) + 255) / 256 * 256;
  const size_t xbpad = (((size_t)N*D*2) + 255) / 256 * 256;
  int*    slots = (int*)d_out;
  ushort* xb    = (ushort*)((char*)d_out + slpad);
  int2*   pairs = (int2*)((char*)d_out + slpad + xbpad);

  hipMemsetAsync(bcnt, 0, 2304 + 1536*sizeof(float), stream);

  const long long n4 = (long long)N * D / 4;

  // --- casts / weight prep ---
  k_xcast<<<2048, 256, 0, stream>>>(x, xb, n4);
  k_wt<<<64, 256, 0, stream>>>(w_self1,  Wb1, 256, 0);
  k_wt<<<64, 256, 0, stream>>>(w_neigh1, Wb1, 256, 128);
  k_wt<<<64, 256, 0, stream>>>(w_self2,  Wb2, 256, 0);
  k_wt<<<64, 256, 0, stream>>>(w_neigh2, Wb2, 256, 128);
  k_wt<<<64, 256, 0, stream>>>(w_skip,   Wb3, 128, 0);

  // --- CSR build via 2-level counting sort ---
  k_p0<<<1024, 256, 0, stream>>>(dst, bcnt, E);
  k_bscan<<<1, 1024, 0, stream>>>(bcnt, bbase, bcur, NB, E);
  k_part<<<(E + PCHUNK - 1)/PCHUNK, 256, 0, stream>>>(src, dst, bcur, pairs, E);
  k_sortb<<<NB, 256, 0, stream>>>(pairs, bbase, offs, slots, N, NB);

  const int gablocks = (N + 3) / 4;
  const int gmblocks = (N + 63) / 64;
  const float invN = 1.0f / (float)N;

  // --- layer 1 ---
  k_gatherb<<<gablocks, 256, 0, stream>>>(xb, slots, offs, meanb, N);
  k_mfma<false><<<gmblocks, 256, 0, stream>>>(xb, meanb, Wb1, nullptr, b1, nullptr,
                                              hpre_b, nullptr, sum1, sq1, nullptr, nullptr, N);
  k_bnfin<<<1, 128, 0, stream>>>(sum1, sq1, g1, be1, bnA1, bnB1, invN);
  k_bnrelub<<<4096, 256, 0, stream>>>(hpre_b, h1b, bnA1, bnB1, n4);

  // --- layer 2 aggregation ---
  k_gatherb<<<gablocks, 256, 0, stream>>>(h1b, slots, offs, meanb, N);

  // fused layer-2 + skip GEMM (shares A fragments; h1b read once)
  k_mfma<true><<<gmblocks, 256, 0, stream>>>(h1b, meanb, Wb2, Wb3, b2, b_skip,
                                             hpre_b, skip_b, sum2, sq2, sum3, sq3, N);
  k_bnfin<<<1, 128, 0, stream>>>(sum2, sq2, g2, be2, bnA2, bnB2, invN);
  k_bnfin<<<1, 128, 0, stream>>>(sum3, sq3, g3, be3, bnA3, bnB3, invN);

  k_final<<<4096, 256, 0, stream>>>(hpre_b, skip_b, out, bnA2, bnB2, bnA3, bnB3, n4);
}

// Round 5
// 315.760 us; speedup vs baseline: 1.4989x; 1.2542x over previous
//
#include <hip/hip_runtime.h>

#define D 128
#define PCHUNK 4096
#define SCAP 8192

typedef short bf16x8 __attribute__((ext_vector_type(8)));
typedef float f32x4 __attribute__((ext_vector_type(4)));

__device__ __forceinline__ ushort f2b(float f){
  unsigned u = __builtin_bit_cast(unsigned, f);
  u += 0x7fffu + ((u >> 16) & 1u);          // round-to-nearest-even
  return (ushort)(u >> 16);
}
__device__ __forceinline__ float b2f(ushort h){
  unsigned u = ((unsigned)h) << 16;
  return __builtin_bit_cast(float, u);
}

// ---------------- P0: coarse bucket histogram (bucket = dst>>8) ----------------
__global__ __launch_bounds__(256) void k_p0(const int* __restrict__ dst,
                                            int* __restrict__ bcnt, int E){
  __shared__ int h[512];
  for (int u=threadIdx.x; u<512; u+=256) h[u]=0;
  __syncthreads();
  for (long long i=(long long)blockIdx.x*256+threadIdx.x; i<E; i+=(long long)gridDim.x*256)
    atomicAdd(&h[dst[i]>>8], 1);
  __syncthreads();
  for (int u=threadIdx.x; u<512; u+=256) if (h[u]) atomicAdd(&bcnt[u], h[u]);
}

// ---------------- P1: scan buckets -> base & cursor ----------------
__global__ void k_bscan(const int* __restrict__ bcnt, int* __restrict__ bbase,
                        int* __restrict__ bcur, int nb, int E){
  __shared__ int sh[1024];
  int t = threadIdx.x;
  int v = (t<nb) ? bcnt[t] : 0;
  sh[t]=v; __syncthreads();
  for (int off=1; off<1024; off<<=1){
    int add = (t>=off)?sh[t-off]:0;
    __syncthreads();
    sh[t]+=add;
    __syncthreads();
  }
  if (t<nb){ int e=sh[t]-v; bbase[t]=e; bcur[t]=e; }
  if (t==nb) bbase[t]=E;
}

// ---------------- P2: LDS-binned partition of (src,dst) into buckets ----------------
__global__ __launch_bounds__(256) void k_part(const int* __restrict__ src,
        const int* __restrict__ dst, int* __restrict__ bcur,
        int2* __restrict__ pairs, int E){
  __shared__ int hist[512], offA[512], offB[512], gbase[512];
  __shared__ int sS[PCHUNK], sD[PCHUNK];
  const int t = threadIdx.x;
  const int base = blockIdx.x * PCHUNK;
  const int cnt = min(PCHUNK, E - base);
  for (int u=t; u<512; u+=256) hist[u]=0;
  __syncthreads();
  int rs[16], rd[16];
  #pragma unroll
  for (int j=0;j<16;j++){
    int li = j*256 + t;
    if (li < cnt){
      rs[j]=src[base+li]; rd[j]=dst[base+li];
      atomicAdd(&hist[rd[j]>>8],1);
    } else { rs[j]=0; rd[j]=-1; }
  }
  __syncthreads();
  int *cur=offA, *nxt=offB;
  for (int u=t; u<512; u+=256) cur[u]=hist[u];
  __syncthreads();
  for (int off=1; off<512; off<<=1){
    for (int u=t; u<512; u+=256) nxt[u] = cur[u] + ((u>=off)?cur[u-off]:0);
    __syncthreads();
    int* tmp=cur; cur=nxt; nxt=tmp;
  }
  for (int u=t; u<512; u+=256) nxt[u] = cur[u]-hist[u];
  __syncthreads();
  #pragma unroll
  for (int j=0;j<16;j++){
    if (j*256+t < cnt){
      int b = rd[j]>>8;
      int p = atomicAdd(&nxt[b],1);
      sS[p]=rs[j]; sD[p]=rd[j];
    }
  }
  __syncthreads();
  for (int u=t; u<512; u+=256){
    int c = hist[u];
    if (c>0) gbase[u] = atomicAdd(&bcur[u], c);
  }
  __syncthreads();
  #pragma unroll
  for (int j=0;j<16;j++){
    int idx = j*256+t;
    if (idx<cnt){
      int d = sD[idx]; int b = d>>8;
      int gpos = gbase[b] + (idx - (cur[b]-hist[b]));
      pairs[gpos] = make_int2(sS[idx], d);
    }
  }
}

// ---------------- P3: per-bucket exact counting sort -> slots + offs ----------------
__global__ __launch_bounds__(256) void k_sortb(const int2* __restrict__ pairs,
        const int* __restrict__ bbase, int* __restrict__ offs,
        int* __restrict__ slots, int N, int NB){
  __shared__ int nh[256], nc[256], sc[256];
  __shared__ int stage[SCAP];
  const int b = blockIdx.x, t = threadIdx.x;
  const int base = bbase[b];
  const int cnt  = bbase[b+1] - base;
  nh[t]=0; __syncthreads();
  for (int i=t;i<cnt;i+=256) atomicAdd(&nh[pairs[base+i].y & 255],1);
  __syncthreads();
  int v = nh[t];
  sc[t]=v; __syncthreads();
  for (int off=1; off<256; off<<=1){
    int add = (t>=off)?sc[t-off]:0;
    __syncthreads();
    sc[t]+=add;
    __syncthreads();
  }
  int excl = sc[t]-v;
  nc[t]=excl;
  int node = (b<<8)+t;
  if (node<N) offs[node]=base+excl;
  if (b==NB-1 && t==0) offs[N]=bbase[NB];
  __syncthreads();
  if (cnt<=SCAP){
    for (int i=t;i<cnt;i+=256){
      int2 p = pairs[base+i];
      int pos = atomicAdd(&nc[p.y & 255],1);
      stage[pos]=p.x;
    }
    __syncthreads();
    for (int i=t;i<cnt;i+=256) slots[base+i]=stage[i];
  } else {
    for (int i=t;i<cnt;i+=256){
      int2 p = pairs[base+i];
      int pos = atomicAdd(&nc[p.y & 255],1);
      slots[base+pos]=p.x;
    }
  }
}

// ---------------- f32 -> bf16 cast ----------------
__global__ __launch_bounds__(256) void k_xcast(const float* __restrict__ x,
                                               ushort* __restrict__ xb, long long n4){
  long long i = (long long)blockIdx.x*256 + threadIdx.x;
  const long long stride = (long long)gridDim.x*256;
  for (; i < n4; i += stride){
    float4 v = reinterpret_cast<const float4*>(x)[i];
    ushort4 o;
    o.x = f2b(v.x); o.y = f2b(v.y); o.z = f2b(v.z); o.w = f2b(v.w);
    reinterpret_cast<ushort4*>(xb)[i] = o;
  }
}

// ---------------- weight transpose+cast: Wb[c*K + k0 + k] = bf16(W[k][c]) ----------------
__global__ void k_wt(const float* __restrict__ W, ushort* __restrict__ Wb, int K, int k0){
  int idx = blockIdx.x*256 + threadIdx.x;   // 0..16383
  int k = idx >> 7, c = idx & 127;
  Wb[(size_t)c*K + k0 + k] = f2b(W[idx]);
}

// ---------------- gather-mean (bf16 in/out): 64 threads/node, pipelined 8-edge groups ----
__global__ __launch_bounds__(256) void k_gatherb(const ushort* __restrict__ Xb,
        const int* __restrict__ slots, const int* __restrict__ offs,
        ushort* __restrict__ meanb, int N){
  int node = blockIdx.x*4 + (threadIdx.x >> 6);
  int c2 = (threadIdx.x & 63) * 2;            // this lane's channel pair
  if (node >= N) return;
  const int beg = offs[node], end = offs[node+1];
  float sx0=0,sy0=0,sx1=0,sy1=0,sx2=0,sy2=0,sx3=0,sy3=0;
  int j = beg;
  while (j < end && (j & 3)){
    unsigned u = *reinterpret_cast<const unsigned*>(&Xb[(size_t)slots[j]*D + c2]);
    sx0 += b2f((ushort)u); sy0 += b2f((ushort)(u>>16));
    ++j;
  }
  const int nfull = (end - j) >> 2;
  const int4* sp = reinterpret_cast<const int4*>(slots + j);

#define G8(ia, ib) { \
    unsigned u0 = *reinterpret_cast<const unsigned*>(&Xb[(size_t)(ia).x*D + c2]); \
    unsigned u1 = *reinterpret_cast<const unsigned*>(&Xb[(size_t)(ia).y*D + c2]); \
    unsigned u2 = *reinterpret_cast<const unsigned*>(&Xb[(size_t)(ia).z*D + c2]); \
    unsigned u3 = *reinterpret_cast<const unsigned*>(&Xb[(size_t)(ia).w*D + c2]); \
    unsigned u4 = *reinterpret_cast<const unsigned*>(&Xb[(size_t)(ib).x*D + c2]); \
    unsigned u5 = *reinterpret_cast<const unsigned*>(&Xb[(size_t)(ib).y*D + c2]); \
    unsigned u6 = *reinterpret_cast<const unsigned*>(&Xb[(size_t)(ib).z*D + c2]); \
    unsigned u7 = *reinterpret_cast<const unsigned*>(&Xb[(size_t)(ib).w*D + c2]); \
    sx0 += b2f((ushort)u0); sy0 += b2f((ushort)(u0>>16)); \
    sx1 += b2f((ushort)u1); sy1 += b2f((ushort)(u1>>16)); \
    sx2 += b2f((ushort)u2); sy2 += b2f((ushort)(u2>>16)); \
    sx3 += b2f((ushort)u3); sy3 += b2f((ushort)(u3>>16)); \
    sx0 += b2f((ushort)u4); sy0 += b2f((ushort)(u4>>16)); \
    sx1 += b2f((ushort)u5); sy1 += b2f((ushort)(u5>>16)); \
    sx2 += b2f((ushort)u6); sy2 += b2f((ushort)(u6>>16)); \
    sx3 += b2f((ushort)u7); sy3 += b2f((ushort)(u7>>16)); }

  int g = 0;
  if (nfull >= 2){
    int4 ia = sp[0], ib = sp[1];
    for (g = 2; g + 2 <= nfull; g += 2){
      int4 na = sp[g], nb = sp[g+1];
      G8(ia, ib);
      ia = na; ib = nb;
    }
    G8(ia, ib);
  }
  if (g < nfull){
    int4 ia = sp[g];
    unsigned u0 = *reinterpret_cast<const unsigned*>(&Xb[(size_t)ia.x*D + c2]);
    unsigned u1 = *reinterpret_cast<const unsigned*>(&Xb[(size_t)ia.y*D + c2]);
    unsigned u2 = *reinterpret_cast<const unsigned*>(&Xb[(size_t)ia.z*D + c2]);
    unsigned u3 = *reinterpret_cast<const unsigned*>(&Xb[(size_t)ia.w*D + c2]);
    sx0 += b2f((ushort)u0); sy0 += b2f((ushort)(u0>>16));
    sx1 += b2f((ushort)u1); sy1 += b2f((ushort)(u1>>16));
    sx2 += b2f((ushort)u2); sy2 += b2f((ushort)(u2>>16));
    sx3 += b2f((ushort)u3); sy3 += b2f((ushort)(u3>>16));
  }
  j += 4*nfull;
  for (; j < end; ++j){
    unsigned u = *reinterpret_cast<const unsigned*>(&Xb[(size_t)slots[j]*D + c2]);
    sx0 += b2f((ushort)u); sy0 += b2f((ushort)(u>>16));
  }
#undef G8
  float deg = (float)(end - beg);
  float rc = deg > 0.f ? 1.0f/deg : 0.f;
  unsigned o = (unsigned)f2b((sx0+sx1+sx2+sx3)*rc)
             | ((unsigned)f2b((sy0+sy1+sy2+sy3)*rc) << 16);
  *reinterpret_cast<unsigned*>(&meanb[(size_t)node*D + c2]) = o;
}

// ---------------- persistent 2-phase pipelined MFMA GEMM, 4-deep lookahead ----------------
// 64x128 tile, 4 waves (2x2). C = [A0 | A1] @ Wb^T + bias (K=256),
// optional fused skip Ck = A0 @ Wk^T + biasK (K=128).
// Grid = 512 persistent blocks (2/CU); each block loops over ~3 row tiles with the
// pipeline never draining across tiles. 4 named register load-sets: loads for step
// s+4 issue at step s, ds_write consumes a set issued 3 steps earlier (~500+ cyc
// latency cover). Raw s_barrier with lgkmcnt(0) only (counted vmcnt, never 0).
// BN stats accumulate in registers across tiles; one atomic phase per block.
template<bool SKIP>
__global__ __launch_bounds__(256, 2) void k_mfma(
    const ushort* __restrict__ A0, const ushort* __restrict__ A1,
    const ushort* __restrict__ Wb, const ushort* __restrict__ Wk,
    const float* __restrict__ bias, const float* __restrict__ biasK,
    ushort* __restrict__ C, ushort* __restrict__ Ck,
    float* __restrict__ gS, float* __restrict__ gQ,
    float* __restrict__ gSK, float* __restrict__ gQK, int N, int NT)
{
  __shared__ ushort At[2][64][40];
  __shared__ ushort Wt[2][128][40];
  __shared__ ushort Wkt[SKIP ? 2*128*40 : 1];
  __shared__ float shS[128], shQ[128], shSK[SKIP?128:1], shQK[SKIP?128:1];
  const int tid = threadIdx.x;
  if (tid < 128){ shS[tid]=0.f; shQ[tid]=0.f; if (SKIP){ shSK[tid]=0.f; shQK[tid]=0.f; } }
  const int bid = blockIdx.x, gridN = gridDim.x;
  const int lane = tid & 63, wid = tid >> 6;
  const int wr = wid >> 1, wc = wid & 1;
  const int lr = lane & 15, kq = lane >> 4;
  const int srA = tid >> 2, s8A = (tid & 3) * 8;
  const int srW = tid >> 2, s8W = (tid & 3) * 8;

  // 4 named register load-sets (period 4 divides the 8-step tile -> static naming)
  int4 va0, va1, va2, va3;
  int4 w0a,w0b, w1a,w1b, w2a,w2b, w3a,w3b;
  int4 k0a,k0b, k1a,k1b, k2a,k2b, k3a,k3b;

#define LOADSET(S, GT, TT) { \
    int grow_ = (GT)*64 + srA; if (grow_ >= N) grow_ = N-1; \
    const ushort* As_ = ((TT) >= 4) ? A1 : A0; \
    va##S = *reinterpret_cast<const int4*>(&As_[(size_t)grow_*D + ((TT)&3)*32 + s8A]); \
    w##S##a = *reinterpret_cast<const int4*>(&Wb[(size_t)srW*256 + (TT)*32 + s8W]); \
    w##S##b = *reinterpret_cast<const int4*>(&Wb[(size_t)(srW+64)*256 + (TT)*32 + s8W]); \
    if (SKIP && (TT) < 4){ \
      k##S##a = *reinterpret_cast<const int4*>(&Wk[(size_t)srW*128 + (TT)*32 + s8W]); \
      k##S##b = *reinterpret_cast<const int4*>(&Wk[(size_t)(srW+64)*128 + (TT)*32 + s8W]); \
    } }

#define WRITESET(S, BW, TT) { \
    *reinterpret_cast<int4*>(&At[BW][srA][s8A]) = va##S; \
    *reinterpret_cast<int4*>(&Wt[BW][srW][s8W]) = w##S##a; \
    *reinterpret_cast<int4*>(&Wt[BW][srW+64][s8W]) = w##S##b; \
    if (SKIP && (TT) < 4){ \
      *reinterpret_cast<int4*>(&Wkt[((BW)*128 + srW)*40 + s8W]) = k##S##a; \
      *reinterpret_cast<int4*>(&Wkt[((BW)*128 + srW + 64)*40 + s8W]) = k##S##b; \
    } }

#define PBAR() { asm volatile("s_waitcnt lgkmcnt(0)" ::: "memory"); \
    __builtin_amdgcn_s_barrier(); __builtin_amdgcn_sched_barrier(0); }

// one k-step: ds_read frags from buf BR, issue lookahead loads (__VA_ARGS__), MFMA
#define STEPBODY(BR, WITHK, ...) { \
    bf16x8 af0 = *reinterpret_cast<const bf16x8*>(&At[BR][32*wr + lr][kq*8]); \
    bf16x8 af1 = *reinterpret_cast<const bf16x8*>(&At[BR][32*wr + 16 + lr][kq*8]); \
    bf16x8 bw0 = *reinterpret_cast<const bf16x8*>(&Wt[BR][64*wc + lr][kq*8]); \
    bf16x8 bw1 = *reinterpret_cast<const bf16x8*>(&Wt[BR][64*wc + 16 + lr][kq*8]); \
    bf16x8 bw2 = *reinterpret_cast<const bf16x8*>(&Wt[BR][64*wc + 32 + lr][kq*8]); \
    bf16x8 bw3 = *reinterpret_cast<const bf16x8*>(&Wt[BR][64*wc + 48 + lr][kq*8]); \
    bf16x8 bk0{}, bk1{}, bk2{}, bk3{}; \
    if (SKIP && (WITHK)){ \
      bk0 = *reinterpret_cast<const bf16x8*>(&Wkt[((BR)*128 + 64*wc + lr)*40 + kq*8]); \
      bk1 = *reinterpret_cast<const bf16x8*>(&Wkt[((BR)*128 + 64*wc + 16 + lr)*40 + kq*8]); \
      bk2 = *reinterpret_cast<const bf16x8*>(&Wkt[((BR)*128 + 64*wc + 32 + lr)*40 + kq*8]); \
      bk3 = *reinterpret_cast<const bf16x8*>(&Wkt[((BR)*128 + 64*wc + 48 + lr)*40 + kq*8]); \
    } \
    __VA_ARGS__; \
    acc[0][0] = __builtin_amdgcn_mfma_f32_16x16x32_bf16(af0, bw0, acc[0][0], 0,0,0); \
    acc[0][1] = __builtin_amdgcn_mfma_f32_16x16x32_bf16(af0, bw1, acc[0][1], 0,0,0); \
    acc[0][2] = __builtin_amdgcn_mfma_f32_16x16x32_bf16(af0, bw2, acc[0][2], 0,0,0); \
    acc[0][3] = __builtin_amdgcn_mfma_f32_16x16x32_bf16(af0, bw3, acc[0][3], 0,0,0); \
    acc[1][0] = __builtin_amdgcn_mfma_f32_16x16x32_bf16(af1, bw0, acc[1][0], 0,0,0); \
    acc[1][1] = __builtin_amdgcn_mfma_f32_16x16x32_bf16(af1, bw1, acc[1][1], 0,0,0); \
    acc[1][2] = __builtin_amdgcn_mfma_f32_16x16x32_bf16(af1, bw2, acc[1][2], 0,0,0); \
    acc[1][3] = __builtin_amdgcn_mfma_f32_16x16x32_bf16(af1, bw3, acc[1][3], 0,0,0); \
    if (SKIP && (WITHK)){ \
      accK[0][0] = __builtin_amdgcn_mfma_f32_16x16x32_bf16(af0, bk0, accK[0][0], 0,0,0); \
      accK[0][1] = __builtin_amdgcn_mfma_f32_16x16x32_bf16(af0, bk1, accK[0][1], 0,0,0); \
      accK[0][2] = __builtin_amdgcn_mfma_f32_16x16x32_bf16(af0, bk2, accK[0][2], 0,0,0); \
      accK[0][3] = __builtin_amdgcn_mfma_f32_16x16x32_bf16(af0, bk3, accK[0][3], 0,0,0); \
      accK[1][0] = __builtin_amdgcn_mfma_f32_16x16x32_bf16(af1, bk0, accK[1][0], 0,0,0); \
      accK[1][1] = __builtin_amdgcn_mfma_f32_16x16x32_bf16(af1, bk1, accK[1][1], 0,0,0); \
      accK[1][2] = __builtin_amdgcn_mfma_f32_16x16x32_bf16(af1, bk2, accK[1][2], 0,0,0); \
      accK[1][3] = __builtin_amdgcn_mfma_f32_16x16x32_bf16(af1, bk3, accK[1][3], 0,0,0); \
    } }

  f32x4 acc[2][4], accK[SKIP?2:1][SKIP?4:1];
  #pragma unroll
  for (int m=0;m<2;m++)
    #pragma unroll
    for (int n=0;n<4;n++){
      acc[m][n] = (f32x4){0.f,0.f,0.f,0.f};
      if (SKIP) accK[m][n] = (f32x4){0.f,0.f,0.f,0.f};
    }
  float bs[4]={0,0,0,0}, bq[4]={0,0,0,0}, bsk[4]={0,0,0,0}, bqk[4]={0,0,0,0};
  float bv[4], bkv[4];
  #pragma unroll
  for (int n=0;n<4;n++){
    bv[n] = bias[64*wc + 16*n + lr];
    bkv[n] = SKIP ? biasK[64*wc + 16*n + lr] : 0.f;
  }

  // prologue: prime 4 sets (steps 0..3 of first tile), stage step 0 into buf0
  {
    const int t0 = bid;
    LOADSET(0, t0, 0);
    LOADSET(1, t0, 1);
    LOADSET(2, t0, 2);
    LOADSET(3, t0, 3);
    WRITESET(0, 0, 0);              // counted vmcnt: waits only set 0 (oldest 5)
    PBAR();
  }

  for (int tile = bid; tile < NT; tile += gridN){
    const int tnext = tile + gridN;
    const bool hasnext = (tnext < NT);
    // t=0..3: lookahead targets steps 4..7 of the CURRENT tile
    STEPBODY(0, 1, LOADSET(0, tile, 4));
    WRITESET(1, 1, 1); PBAR();
    STEPBODY(1, 1, LOADSET(1, tile, 5));
    WRITESET(2, 0, 2); PBAR();
    STEPBODY(0, 1, LOADSET(2, tile, 6));
    WRITESET(3, 1, 3); PBAR();
    STEPBODY(1, 1, LOADSET(3, tile, 7));
    WRITESET(0, 0, 4); PBAR();
    // t=4..7: lookahead targets steps 0..3 of the NEXT tile (guarded)
    STEPBODY(0, 0, if (hasnext) LOADSET(0, tnext, 0));
    WRITESET(1, 1, 5); PBAR();
    STEPBODY(1, 0, if (hasnext) LOADSET(1, tnext, 1));
    WRITESET(2, 0, 6); PBAR();
    STEPBODY(0, 0, if (hasnext) LOADSET(2, tnext, 2));
    WRITESET(3, 1, 7); PBAR();
    STEPBODY(1, 0, if (hasnext) LOADSET(3, tnext, 3));
    if (hasnext){ WRITESET(0, 0, 0); PBAR(); }

    // per-tile epilogue (stores overlap next tile's in-flight loads / ds_reads)
    #pragma unroll
    for (int m=0;m<2;m++){
      #pragma unroll
      for (int r=0;r<4;r++){
        int row = tile*64 + 32*wr + 16*m + kq*4 + r;
        if (row < N){
          #pragma unroll
          for (int n=0;n<4;n++){
            int col = 64*wc + 16*n + lr;
            float v = acc[m][n][r] + bv[n];
            C[(size_t)row*D + col] = f2b(v);
            bs[n] += v; bq[n] += v*v;
            if (SKIP){
              float u = accK[m][n][r] + bkv[n];
              Ck[(size_t)row*D + col] = f2b(u);
              bsk[n] += u; bqk[n] += u*u;
            }
          }
        }
      }
    }
    #pragma unroll
    for (int m=0;m<2;m++)
      #pragma unroll
      for (int n=0;n<4;n++){
        acc[m][n] = (f32x4){0.f,0.f,0.f,0.f};
        if (SKIP) accK[m][n] = (f32x4){0.f,0.f,0.f,0.f};
      }
  }
#undef LOADSET
#undef WRITESET
#undef PBAR
#undef STEPBODY

  // one stat-reduction per block
  #pragma unroll
  for (int n=0;n<4;n++){
    float s = bs[n], q = bq[n];
    s += __shfl_xor(s,16); s += __shfl_xor(s,32);
    q += __shfl_xor(q,16); q += __shfl_xor(q,32);
    if (kq == 0){
      int col = 64*wc + 16*n + lr;
      atomicAdd(&shS[col], s);
      atomicAdd(&shQ[col], q);
    }
    if (SKIP){
      float sk = bsk[n], qk = bqk[n];
      sk += __shfl_xor(sk,16); sk += __shfl_xor(sk,32);
      qk += __shfl_xor(qk,16); qk += __shfl_xor(qk,32);
      if (kq == 0){
        int col = 64*wc + 16*n + lr;
        atomicAdd(&shSK[col], sk);
        atomicAdd(&shQK[col], qk);
      }
    }
  }
  __syncthreads();
  if (tid < 128){
    unsafeAtomicAdd(&gS[tid], shS[tid]);
    unsafeAtomicAdd(&gQ[tid], shQ[tid]);
    if (SKIP){
      unsafeAtomicAdd(&gSK[tid], shSK[tid]);
      unsafeAtomicAdd(&gQK[tid], shQK[tid]);
    }
  }
}

// ---------------- BN finalize ----------------
__global__ void k_bnfin(const float* __restrict__ sum, const float* __restrict__ sq,
                        const float* __restrict__ g, const float* __restrict__ be,
                        float* __restrict__ bnA, float* __restrict__ bnB, float invN){
  int c = threadIdx.x;
  float m = sum[c]*invN;
  float v = sq[c]*invN - m*m;
  float a = g[c]*rsqrtf(fmaxf(v, 0.f) + 1e-5f);
  bnA[c] = a;
  bnB[c] = be[c] - m*a;
}

// ---------------- BN + ReLU, bf16 in -> bf16 out ----------------
__global__ __launch_bounds__(256) void k_bnrelub(const ushort* __restrict__ hpre,
      ushort* __restrict__ hb,
      const float* __restrict__ A, const float* __restrict__ Bp, long long n4){
  long long i = (long long)blockIdx.x*256 + threadIdx.x;
  const long long stride = (long long)gridDim.x*256;
  for (; i < n4; i += stride){
    int c = ((int)(i & 31)) << 2;
    float4 a = *reinterpret_cast<const float4*>(A + c);
    float4 b = *reinterpret_cast<const float4*>(Bp + c);
    ushort4 hv = reinterpret_cast<const ushort4*>(hpre)[i];
    ushort4 o;
    o.x = f2b(fmaxf(a.x*b2f(hv.x) + b.x, 0.f));
    o.y = f2b(fmaxf(a.y*b2f(hv.y) + b.y, 0.f));
    o.z = f2b(fmaxf(a.z*b2f(hv.z) + b.z, 0.f));
    o.w = f2b(fmaxf(a.w*b2f(hv.w) + b.w, 0.f));
    reinterpret_cast<ushort4*>(hb)[i] = o;
  }
}

// ---------------- final: out = relu(bn2(h2) + bn3(skip)), f32 out ----------------
__global__ __launch_bounds__(256) void k_final(const ushort* __restrict__ h2,
      const ushort* __restrict__ sk, float* __restrict__ out,
      const float* __restrict__ A2, const float* __restrict__ B2,
      const float* __restrict__ A3, const float* __restrict__ B3, long long n4){
  long long i = (long long)blockIdx.x*256 + threadIdx.x;
  const long long stride = (long long)gridDim.x*256;
  for (; i < n4; i += stride){
    int c = ((int)(i & 31)) << 2;
    float4 a2 = *reinterpret_cast<const float4*>(A2 + c);
    float4 b2 = *reinterpret_cast<const float4*>(B2 + c);
    float4 a3 = *reinterpret_cast<const float4*>(A3 + c);
    float4 b3 = *reinterpret_cast<const float4*>(B3 + c);
    ushort4 h = reinterpret_cast<const ushort4*>(h2)[i];
    ushort4 s = reinterpret_cast<const ushort4*>(sk)[i];
    float4 v;
    v.x = fmaxf(a2.x*b2f(h.x) + b2.x + a3.x*b2f(s.x) + b3.x, 0.f);
    v.y = fmaxf(a2.y*b2f(h.y) + b2.y + a3.y*b2f(s.y) + b3.y, 0.f);
    v.z = fmaxf(a2.z*b2f(h.z) + b2.z + a3.z*b2f(s.z) + b3.z, 0.f);
    v.w = fmaxf(a2.w*b2f(h.w) + b2.w + a3.w*b2f(s.w) + b3.w, 0.f);
    reinterpret_cast<float4*>(out)[i] = v;
  }
}

extern "C" void kernel_launch(void* const* d_in, const int* in_sizes, int n_in,
                              void* d_out, int out_size, void* d_ws, size_t ws_size,
                              hipStream_t stream) {
  const float* x        = (const float*)d_in[0];
  const int*   src      = (const int*)  d_in[1];
  const int*   dst      = (const int*)  d_in[2];
  const float* w_self1  = (const float*)d_in[3];
  const float* w_neigh1 = (const float*)d_in[4];
  const float* b1       = (const float*)d_in[5];
  const float* w_self2  = (const float*)d_in[6];
  const float* w_neigh2 = (const float*)d_in[7];
  const float* b2       = (const float*)d_in[8];
  const float* w_skip   = (const float*)d_in[9];
  const float* b_skip   = (const float*)d_in[10];
  const float* g1       = (const float*)d_in[11];
  const float* be1      = (const float*)d_in[12];
  const float* g2       = (const float*)d_in[13];
  const float* be2      = (const float*)d_in[14];
  const float* g3       = (const float*)d_in[15];
  const float* be3      = (const float*)d_in[16];
  (void)n_in; (void)ws_size;

  const int N = in_sizes[0] / D;
  const int E = in_sizes[1];
  const int NB = (N + 255) >> 8;
  float* out = (float*)d_out;

  // ---- workspace layout ----
  char* p = (char*)d_ws;
  const size_t nd2 = (((size_t)N * D * 2) + 255) / 256 * 256;   // bf16 [N][D]
  ushort* meanb  = (ushort*)p; p += nd2;
  ushort* h1b    = (ushort*)p; p += nd2;
  ushort* hpre_b = (ushort*)p; p += nd2;     // h1pre, then h2pre (aliased)
  ushort* skip_b = (ushort*)p; p += nd2;
  ushort* Wb1    = (ushort*)p; p += 256*128*2;
  ushort* Wb2    = (ushort*)p; p += 256*128*2;
  ushort* Wb3    = (ushort*)p; p += 128*128*2;
  int*    offs   = (int*)p;   p += (((size_t)(N+1)*4) + 255) / 256 * 256;
  int*    bcnt   = (int*)p;   p += 2304;
  float*  st     = (float*)p; p += 1536*sizeof(float);
  int*    bbase  = (int*)p;   p += 2304;
  int*    bcur   = (int*)p;   p += 2048;
  float *sum1=st,      *sq1=st+128,  *sum2=st+256, *sq2=st+384, *sum3=st+512, *sq3=st+640;
  float *bnA1=st+768,  *bnB1=st+896, *bnA2=st+1024,*bnB2=st+1152,*bnA3=st+1280,*bnB3=st+1408;

  // scratch in d_out (dead before k_final rewrites all of d_out)
  const size_t slpad = (((size_t)E*4) + 255) / 256 * 256;
  const size_t xbpad = (((size_t)N*D*2) + 255) / 256 * 256;
  int*    slots = (int*)d_out;
  ushort* xb    = (ushort*)((char*)d_out + slpad);
  int2*   pairs = (int2*)((char*)d_out + slpad + xbpad);

  hipMemsetAsync(bcnt, 0, 2304 + 1536*sizeof(float), stream);

  const long long n4 = (long long)N * D / 4;

  // --- casts / weight prep ---
  k_xcast<<<2048, 256, 0, stream>>>(x, xb, n4);
  k_wt<<<64, 256, 0, stream>>>(w_self1,  Wb1, 256, 0);
  k_wt<<<64, 256, 0, stream>>>(w_neigh1, Wb1, 256, 128);
  k_wt<<<64, 256, 0, stream>>>(w_self2,  Wb2, 256, 0);
  k_wt<<<64, 256, 0, stream>>>(w_neigh2, Wb2, 256, 128);
  k_wt<<<64, 256, 0, stream>>>(w_skip,   Wb3, 128, 0);

  // --- CSR build via 2-level counting sort ---
  k_p0<<<1024, 256, 0, stream>>>(dst, bcnt, E);
  k_bscan<<<1, 1024, 0, stream>>>(bcnt, bbase, bcur, NB, E);
  k_part<<<(E + PCHUNK - 1)/PCHUNK, 256, 0, stream>>>(src, dst, bcur, pairs, E);
  k_sortb<<<NB, 256, 0, stream>>>(pairs, bbase, offs, slots, N, NB);

  const int gablocks = (N + 3) / 4;
  const int NT = (N + 63) / 64;
  const int gpersist = 512;                 // 2 persistent blocks per CU
  const float invN = 1.0f / (float)N;

  // --- layer 1 ---
  k_gatherb<<<gablocks, 256, 0, stream>>>(xb, slots, offs, meanb, N);
  k_mfma<false><<<gpersist, 256, 0, stream>>>(xb, meanb, Wb1, nullptr, b1, nullptr,
                                              hpre_b, nullptr, sum1, sq1, nullptr, nullptr, N, NT);
  k_bnfin<<<1, 128, 0, stream>>>(sum1, sq1, g1, be1, bnA1, bnB1, invN);
  k_bnrelub<<<4096, 256, 0, stream>>>(hpre_b, h1b, bnA1, bnB1, n4);

  // --- layer 2 aggregation ---
  k_gatherb<<<gablocks, 256, 0, stream>>>(h1b, slots, offs, meanb, N);

  // fused layer-2 + skip GEMM (shares A fragments; h1b read once)
  k_mfma<true><<<gpersist, 256, 0, stream>>>(h1b, meanb, Wb2, Wb3, b2, b_skip,
                                             hpre_b, skip_b, sum2, sq2, sum3, sq3, N, NT);
  k_bnfin<<<1, 128, 0, stream>>>(sum2, sq2, g2, be2, bnA2, bnB2, invN);
  k_bnfin<<<1, 128, 0, stream>>>(sum3, sq3, g3, be3, bnA3, bnB3, invN);

  k_final<<<4096, 256, 0, stream>>>(hpre_b, skip_b, out, bnA2, bnB2, bnA3, bnB3, n4);
}